// Round 5
// baseline (3545.460 us; speedup 1.0000x reference)
//
#include <hip/hip_runtime.h>
#include <cmath>

#define NB 4
#define TT 2048
#define DD 256
#define NH 4
#define BT (NB*TT)   // 8192 rows

static constexpr float DT_ = 0.25f;

typedef _Float16 f16x8 __attribute__((ext_vector_type(8)));
typedef _Float16 f16x4 __attribute__((ext_vector_type(4)));
typedef float    f32x4 __attribute__((ext_vector_type(4)));

static constexpr size_t HSZ = (size_t)NB * NH * TT * 64;   // per split Q/K array: 2M halves

// ---------------- split W into fp16 hi/lo (runs once per launch) ----------------
__global__ __launch_bounds__(256)
void split_weights(const float* __restrict__ Wqk, const float* __restrict__ Wout,
                   _Float16* __restrict__ WqkH, _Float16* __restrict__ WqkL,
                   _Float16* __restrict__ WoutH, _Float16* __restrict__ WoutL)
{
    const int idx = blockIdx.x * 256 + threadIdx.x;   // float4 group index
    const float4 v = (idx < 32768) ? ((const float4*)Wqk)[idx]
                                   : ((const float4*)Wout)[idx - 32768];
    f16x4 h, l;
    h[0]=(_Float16)v.x; l[0]=(_Float16)(v.x-(float)h[0]);
    h[1]=(_Float16)v.y; l[1]=(_Float16)(v.y-(float)h[1]);
    h[2]=(_Float16)v.z; l[2]=(_Float16)(v.z-(float)h[2]);
    h[3]=(_Float16)v.w; l[3]=(_Float16)(v.w-(float)h[3]);
    if (idx < 32768) { ((f16x4*)WqkH)[idx] = h; ((f16x4*)WqkL)[idx] = l; }
    else { ((f16x4*)WoutH)[idx-32768] = h; ((f16x4*)WoutL)[idx-32768] = l; }
}

// ---------------- row-wise l2 norm over D=256; optional fp16 split emit ----------------
__global__ __launch_bounds__(256)
void l2norm_rows(const float* __restrict__ src, float* __restrict__ dst,
                 _Float16* __restrict__ dstH, _Float16* __restrict__ dstL) {
    const int wave = threadIdx.x >> 6;
    const int lane = threadIdx.x & 63;
    const size_t row = (size_t)blockIdx.x * 4 + wave;
    float4 v = ((const float4*)(src + row * DD))[lane];
    float ss = v.x*v.x + v.y*v.y + v.z*v.z + v.w*v.w;
    #pragma unroll
    for (int off = 32; off; off >>= 1) ss += __shfl_xor(ss, off, 64);
    const float inv = 1.0f / fmaxf(sqrtf(ss), 1e-12f);
    v.x *= inv; v.y *= inv; v.z *= inv; v.w *= inv;
    ((float4*)(dst + row * DD))[lane] = v;
    if (dstH != nullptr) {
        f16x4 h, l;
        h[0]=(_Float16)v.x; l[0]=(_Float16)(v.x-(float)h[0]);
        h[1]=(_Float16)v.y; l[1]=(_Float16)(v.y-(float)h[1]);
        h[2]=(_Float16)v.z; l[2]=(_Float16)(v.z-(float)h[2]);
        h[3]=(_Float16)v.w; l[3]=(_Float16)(v.w-(float)h[3]);
        ((f16x4*)(dstH + row * DD))[lane] = h;
        ((f16x4*)(dstL + row * DD))[lane] = l;
    }
}

// ---------------- split-fp16 MFMA GEMM: C = A[M,256] * W[N,256]^T ----------------
// (unchanged from R4 — passing) Block 256 thr / 4 waves; tile 128m x 64n.
__global__ __launch_bounds__(256)
void gemm_mfma(const _Float16* __restrict__ AH, const _Float16* __restrict__ AL,
               const _Float16* __restrict__ BH, const _Float16* __restrict__ BL,
               const float* __restrict__ omega, const float* __restrict__ bout,
               const float* __restrict__ xin, float* __restrict__ kacc,
               _Float16* __restrict__ xsH, _Float16* __restrict__ xsL,
               float* __restrict__ xout,
               _Float16* __restrict__ Qhi, _Float16* __restrict__ Qlo,
               _Float16* __restrict__ Khi, _Float16* __restrict__ Klo,
               _Float16* __restrict__ KtrH, _Float16* __restrict__ KtrL,
               int stage)
{
    __shared__ _Float16 Ah[128 * 72];
    __shared__ _Float16 Al[128 * 72];
    __shared__ _Float16 Bh[64 * 72];
    __shared__ _Float16 Bl[64 * 72];
    const int m0 = blockIdx.x * 128, n0 = blockIdx.y * 64;
    const int t  = threadIdx.x;
    const int w  = t >> 6;
    const int l  = t & 63;
    const int lr = l & 15;
    const int lq = l >> 4;

    f32x4 acc[2][4];
    #pragma unroll
    for (int s = 0; s < 2; ++s)
        #pragma unroll
        for (int nt = 0; nt < 4; ++nt) acc[s][nt] = (f32x4){0.f,0.f,0.f,0.f};

    for (int kc = 0; kc < 4; ++kc) {
        const int k0 = kc * 64;
        __syncthreads();
        #pragma unroll
        for (int s2 = 0; s2 < 4; ++s2) {
            const int idx = t + 256 * s2;
            const int r = idx >> 3, c8 = (idx & 7) * 8;
            *(uint4*)&Ah[r * 72 + c8] = *(const uint4*)(AH + (size_t)(m0 + r) * 256 + k0 + c8);
            *(uint4*)&Al[r * 72 + c8] = *(const uint4*)(AL + (size_t)(m0 + r) * 256 + k0 + c8);
        }
        #pragma unroll
        for (int s2 = 0; s2 < 2; ++s2) {
            const int idx = t + 256 * s2;
            const int r = idx >> 3, c8 = (idx & 7) * 8;
            *(uint4*)&Bh[r * 72 + c8] = *(const uint4*)(BH + (size_t)(n0 + r) * 256 + k0 + c8);
            *(uint4*)&Bl[r * 72 + c8] = *(const uint4*)(BL + (size_t)(n0 + r) * 256 + k0 + c8);
        }
        __syncthreads();
        #pragma unroll
        for (int c = 0; c < 2; ++c) {
            f16x8 ah[2], al[2], bh[4], bl[4];
            #pragma unroll
            for (int s = 0; s < 2; ++s) {
                ah[s] = *(const f16x8*)&Ah[(32*w + 16*s + lr) * 72 + 32*c + 8*lq];
                al[s] = *(const f16x8*)&Al[(32*w + 16*s + lr) * 72 + 32*c + 8*lq];
            }
            #pragma unroll
            for (int nt = 0; nt < 4; ++nt) {
                bh[nt] = *(const f16x8*)&Bh[(16*nt + lr) * 72 + 32*c + 8*lq];
                bl[nt] = *(const f16x8*)&Bl[(16*nt + lr) * 72 + 32*c + 8*lq];
            }
            #pragma unroll
            for (int s = 0; s < 2; ++s)
                #pragma unroll
                for (int nt = 0; nt < 4; ++nt) {
                    acc[s][nt] = __builtin_amdgcn_mfma_f32_16x16x32_f16(ah[s], bh[nt], acc[s][nt], 0, 0, 0);
                    acc[s][nt] = __builtin_amdgcn_mfma_f32_16x16x32_f16(ah[s], bl[nt], acc[s][nt], 0, 0, 0);
                    acc[s][nt] = __builtin_amdgcn_mfma_f32_16x16x32_f16(al[s], bh[nt], acc[s][nt], 0, 0, 0);
                }
        }
    }

    if (stage < 0) {
        float ss[2][4];
        #pragma unroll
        for (int s = 0; s < 2; ++s)
            #pragma unroll
            for (int r = 0; r < 4; ++r) {
                float v = 0.f;
                #pragma unroll
                for (int nt = 0; nt < 4; ++nt) v += acc[s][nt][r] * acc[s][nt][r];
                ss[s][r] = v;
            }
        #pragma unroll
        for (int off = 1; off < 16; off <<= 1)
            #pragma unroll
            for (int s = 0; s < 2; ++s)
                #pragma unroll
                for (int r = 0; r < 4; ++r)
                    ss[s][r] += __shfl_xor(ss[s][r], off, 64);
        const int  b    = m0 >> 11;
        const int  h    = (n0 >> 6) & 3;
        const bool is_k = (n0 >= 256);
        const size_t bhi = (size_t)b * NH + h;
        _Float16* dhi = (is_k ? Khi : Qhi) + bhi * (size_t)TT * 64;
        _Float16* dlo = (is_k ? Klo : Qlo) + bhi * (size_t)TT * 64;
        const int mloc = m0 & (TT - 1);
        #pragma unroll
        for (int s = 0; s < 2; ++s) {
            const int r0 = 32*w + 16*s + 4*lq;
            float inv[4];
            #pragma unroll
            for (int r = 0; r < 4; ++r) inv[r] = 1.0f / fmaxf(sqrtf(ss[s][r]), 1e-12f);
            #pragma unroll
            for (int nt = 0; nt < 4; ++nt) {
                const int d = 16*nt + lr;
                f16x4 hv, lv;
                #pragma unroll
                for (int r = 0; r < 4; ++r) {
                    const float val = acc[s][nt][r] * inv[r];
                    hv[r] = (_Float16)val;
                    lv[r] = (_Float16)(val - (float)hv[r]);
                    dhi[(size_t)(mloc + r0 + r) * 64 + d] = hv[r];
                    dlo[(size_t)(mloc + r0 + r) * 64 + d] = lv[r];
                }
                if (is_k) {
                    const size_t tb = bhi * (size_t)64 * TT + (size_t)d * TT + mloc + r0;
                    *(f16x4*)(KtrH + tb) = hv;
                    *(f16x4*)(KtrL + tb) = lv;
                }
            }
        }
    } else {
        #pragma unroll
        for (int s = 0; s < 2; ++s) {
            const int row0 = m0 + 32*w + 16*s + 4*lq;
            #pragma unroll
            for (int nt = 0; nt < 4; ++nt) {
                const int col = n0 + 16*nt + lr;
                const float ob = omega[col] + bout[col];
                #pragma unroll
                for (int r = 0; r < 4; ++r) {
                    const size_t off = (size_t)(row0 + r) * 256 + col;
                    const float f = acc[s][nt][r] + ob;
                    if (stage == 0) {
                        kacc[off] = f;
                        const float xv = xin[off] + 0.125f * f;
                        const _Float16 xh = (_Float16)xv;
                        xsH[off] = xh;
                        xsL[off] = (_Float16)(xv - (float)xh);
                    } else if (stage < 3) {
                        kacc[off] += 2.0f * f;
                        const float c = (stage == 1) ? 0.125f : 0.25f;
                        const float xv = xin[off] + c * f;
                        const _Float16 xh = (_Float16)xv;
                        xsH[off] = xh;
                        xsL[off] = (_Float16)(xv - (float)xh);
                    } else {
                        xout[off] = xin[off] + (DT_ / 6.0f) * (kacc[off] + f);
                    }
                }
            }
        }
    }
}

// unpack interleaved (hi,lo) dword pairs -> hi-frag / lo-frag halves
__device__ inline void unpack_hl(const uint4 a, const uint4 b, f16x8& hi, f16x8& lo) {
    union { unsigned int u[4]; f16x8 v; } H, L;
    H.u[0] = __builtin_amdgcn_perm(a.y, a.x, 0x05040100u);
    L.u[0] = __builtin_amdgcn_perm(a.y, a.x, 0x07060302u);
    H.u[1] = __builtin_amdgcn_perm(a.w, a.z, 0x05040100u);
    L.u[1] = __builtin_amdgcn_perm(a.w, a.z, 0x07060302u);
    H.u[2] = __builtin_amdgcn_perm(b.y, b.x, 0x05040100u);
    L.u[2] = __builtin_amdgcn_perm(b.y, b.x, 0x07060302u);
    H.u[3] = __builtin_amdgcn_perm(b.w, b.z, 0x05040100u);
    L.u[3] = __builtin_amdgcn_perm(b.w, b.z, 0x07060302u);
    hi = H.v; lo = L.v;
}

// ---------------- F = sin(Q K^T) K, split-fp16 MFMA; 128-i tile, 32 rows/wave ----------------
// LDS-instr-minimized: B-frags amortized over 2 i-subtiles; P staged as packed
// (hi,lo) dwords; K-tile global loads register-double-buffered.
__global__ __launch_bounds__(256)
void kuramoto_attn(const _Float16* __restrict__ Qhi, const _Float16* __restrict__ Qlo,
                   const _Float16* __restrict__ Khi, const _Float16* __restrict__ Klo,
                   const _Float16* __restrict__ KtrH, const _Float16* __restrict__ KtrL,
                   _Float16* __restrict__ FH, _Float16* __restrict__ FL)
{
    __shared__ _Float16 KjH[64 * 72];       // [j][d] hi
    __shared__ _Float16 KjL[64 * 72];       // [j][d] lo
    __shared__ _Float16 KdH[64 * 72];       // [d][j] hi
    __shared__ _Float16 KdL[64 * 72];       // [d][j] lo
    __shared__ unsigned int Pw[4][16 * 68]; // per-wave packed (hi,lo) P, pitch 68 dwords
    const int h = blockIdx.y, b = blockIdx.z;
    const size_t bh    = (size_t)b * NH + h;
    const size_t base  = bh * (size_t)TT * 64;
    const size_t tbase = bh * (size_t)64 * TT;
    const int t = threadIdx.x;
    const int w = t >> 6;
    const int l = t & 63;
    const int lr = l & 15;
    const int lq = l >> 4;
    const int i0 = blockIdx.x * 128 + w * 32;

    // Q fragments for both 16-row subtiles, live whole kernel
    f16x8 qh[2][2], ql[2][2];
    #pragma unroll
    for (int s = 0; s < 2; ++s) {
        const size_t qoff = base + (size_t)(i0 + 16*s + lr) * 64 + lq * 8;
        qh[s][0] = *(const f16x8*)(Qhi + qoff);
        qh[s][1] = *(const f16x8*)(Qhi + qoff + 32);
        ql[s][0] = *(const f16x8*)(Qlo + qoff);
        ql[s][1] = *(const f16x8*)(Qlo + qoff + 32);
    }

    f32x4 Facc[2][4];
    #pragma unroll
    for (int s = 0; s < 2; ++s)
        #pragma unroll
        for (int nt = 0; nt < 4; ++nt) Facc[s][nt] = (f32x4){0.f, 0.f, 0.f, 0.f};

    const int sr = t >> 3;       // staging row 0..31 (+32)
    const int so = (t & 7) * 8;  // staging octet offset (halves)

    // register prefetch of tile j0=0
    uint4 g[8];
    {
        g[0] = *(const uint4*)(Khi + base + (size_t)sr * 64 + so);
        g[1] = *(const uint4*)(Khi + base + (size_t)(sr + 32) * 64 + so);
        g[2] = *(const uint4*)(Klo + base + (size_t)sr * 64 + so);
        g[3] = *(const uint4*)(Klo + base + (size_t)(sr + 32) * 64 + so);
        g[4] = *(const uint4*)(KtrH + tbase + (size_t)sr * TT + so);
        g[5] = *(const uint4*)(KtrH + tbase + (size_t)(sr + 32) * TT + so);
        g[6] = *(const uint4*)(KtrL + tbase + (size_t)sr * TT + so);
        g[7] = *(const uint4*)(KtrL + tbase + (size_t)(sr + 32) * TT + so);
    }

    for (int j0 = 0; j0 < TT; j0 += 64) {
        __syncthreads();   // previous tile's LDS reads complete
        *(uint4*)&KjH[sr * 72 + so]        = g[0];
        *(uint4*)&KjH[(sr + 32) * 72 + so] = g[1];
        *(uint4*)&KjL[sr * 72 + so]        = g[2];
        *(uint4*)&KjL[(sr + 32) * 72 + so] = g[3];
        *(uint4*)&KdH[sr * 72 + so]        = g[4];
        *(uint4*)&KdH[(sr + 32) * 72 + so] = g[5];
        *(uint4*)&KdL[sr * 72 + so]        = g[6];
        *(uint4*)&KdL[(sr + 32) * 72 + so] = g[7];
        __syncthreads();
        {   // prefetch next tile (wrapped — always in-bounds) under compute
            const int jn = (j0 + 64) & (TT - 1);
            g[0] = *(const uint4*)(Khi + base + (size_t)(jn + sr) * 64 + so);
            g[1] = *(const uint4*)(Khi + base + (size_t)(jn + sr + 32) * 64 + so);
            g[2] = *(const uint4*)(Klo + base + (size_t)(jn + sr) * 64 + so);
            g[3] = *(const uint4*)(Klo + base + (size_t)(jn + sr + 32) * 64 + so);
            g[4] = *(const uint4*)(KtrH + tbase + (size_t)sr * TT + jn + so);
            g[5] = *(const uint4*)(KtrH + tbase + (size_t)(sr + 32) * TT + jn + so);
            g[6] = *(const uint4*)(KtrL + tbase + (size_t)sr * TT + jn + so);
            g[7] = *(const uint4*)(KtrL + tbase + (size_t)(sr + 32) * TT + jn + so);
        }
        // GEMM1: S[s] (16i x 64j) = Q K^T, B-frags shared by both subtiles
        f32x4 S[2][4];
        #pragma unroll
        for (int nt = 0; nt < 4; ++nt) {
            f16x8 bh0 = *(const f16x8*)&KjH[(16*nt + lr) * 72 + lq * 8];
            f16x8 bh1 = *(const f16x8*)&KjH[(16*nt + lr) * 72 + 32 + lq * 8];
            f16x8 bl0 = *(const f16x8*)&KjL[(16*nt + lr) * 72 + lq * 8];
            f16x8 bl1 = *(const f16x8*)&KjL[(16*nt + lr) * 72 + 32 + lq * 8];
            #pragma unroll
            for (int s = 0; s < 2; ++s) {
                f32x4 acc = (f32x4){0.f, 0.f, 0.f, 0.f};
                acc = __builtin_amdgcn_mfma_f32_16x16x32_f16(qh[s][0], bh0, acc, 0, 0, 0);
                acc = __builtin_amdgcn_mfma_f32_16x16x32_f16(qh[s][1], bh1, acc, 0, 0, 0);
                acc = __builtin_amdgcn_mfma_f32_16x16x32_f16(qh[s][0], bl0, acc, 0, 0, 0);
                acc = __builtin_amdgcn_mfma_f32_16x16x32_f16(qh[s][1], bl1, acc, 0, 0, 0);
                acc = __builtin_amdgcn_mfma_f32_16x16x32_f16(ql[s][0], bh0, acc, 0, 0, 0);
                acc = __builtin_amdgcn_mfma_f32_16x16x32_f16(ql[s][1], bh1, acc, 0, 0, 0);
                S[s][nt] = acc;
            }
        }
        // sin -> packed (hi,lo) -> per-wave LDS round trip -> A-frags (both subtiles)
        f16x8 ph[2][2], pl[2][2];
        #pragma unroll
        for (int s = 0; s < 2; ++s) {
            #pragma unroll
            for (int nt = 0; nt < 4; ++nt)
                #pragma unroll
                for (int r = 0; r < 4; ++r) {
                    const float p = __sinf(S[s][nt][r]);
                    const _Float16 hi = (_Float16)p;
                    const _Float16 lo = (_Float16)(p - (float)hi);
                    const unsigned int pk =
                        ((unsigned int)__builtin_bit_cast(unsigned short, lo) << 16)
                        | (unsigned int)__builtin_bit_cast(unsigned short, hi);
                    Pw[w][(4*lq + r) * 68 + 16*nt + lr] = pk;
                }
            #pragma unroll
            for (int c = 0; c < 2; ++c) {
                const uint4 a = *(const uint4*)&Pw[w][lr * 68 + c * 32 + lq * 8];
                const uint4 bq = *(const uint4*)&Pw[w][lr * 68 + c * 32 + lq * 8 + 4];
                unpack_hl(a, bq, ph[s][c], pl[s][c]);
            }
        }
        // GEMM2: F[s] += P K, B-frags shared by both subtiles
        #pragma unroll
        for (int nt = 0; nt < 4; ++nt) {
            f16x8 kh0 = *(const f16x8*)&KdH[(16*nt + lr) * 72 + lq * 8];
            f16x8 kh1 = *(const f16x8*)&KdH[(16*nt + lr) * 72 + 32 + lq * 8];
            f16x8 kl0 = *(const f16x8*)&KdL[(16*nt + lr) * 72 + lq * 8];
            f16x8 kl1 = *(const f16x8*)&KdL[(16*nt + lr) * 72 + 32 + lq * 8];
            #pragma unroll
            for (int s = 0; s < 2; ++s) {
                Facc[s][nt] = __builtin_amdgcn_mfma_f32_16x16x32_f16(ph[s][0], kh0, Facc[s][nt], 0, 0, 0);
                Facc[s][nt] = __builtin_amdgcn_mfma_f32_16x16x32_f16(ph[s][1], kh1, Facc[s][nt], 0, 0, 0);
                Facc[s][nt] = __builtin_amdgcn_mfma_f32_16x16x32_f16(ph[s][0], kl0, Facc[s][nt], 0, 0, 0);
                Facc[s][nt] = __builtin_amdgcn_mfma_f32_16x16x32_f16(ph[s][1], kl1, Facc[s][nt], 0, 0, 0);
                Facc[s][nt] = __builtin_amdgcn_mfma_f32_16x16x32_f16(pl[s][0], kh0, Facc[s][nt], 0, 0, 0);
                Facc[s][nt] = __builtin_amdgcn_mfma_f32_16x16x32_f16(pl[s][1], kh1, Facc[s][nt], 0, 0, 0);
            }
        }
    }
    // write F splits: row = i0 + 16s + 4lq + r, col = h*64 + 16nt + lr
    #pragma unroll
    for (int s = 0; s < 2; ++s) {
        const size_t fo = ((size_t)b * TT + i0 + 16*s + 4*lq) * 256 + h * 64 + lr;
        #pragma unroll
        for (int nt = 0; nt < 4; ++nt)
            #pragma unroll
            for (int r = 0; r < 4; ++r) {
                const float v = Facc[s][nt][r];
                const _Float16 vh = (_Float16)v;
                FH[fo + (size_t)r * 256 + nt * 16] = vh;
                FL[fo + (size_t)r * 256 + nt * 16] = (_Float16)(v - (float)vh);
            }
    }
}

extern "C" void kernel_launch(void* const* d_in, const int* in_sizes, int n_in,
                              void* d_out, int out_size, void* d_ws, size_t ws_size,
                              hipStream_t stream) {
    const float* z     = (const float*)d_in[0];
    const float* omega = (const float*)d_in[1];
    const float* Wqk   = (const float*)d_in[2];
    const float* Wout  = (const float*)d_in[3];
    const float* bout  = (const float*)d_in[4];

    float* x    = (float*)d_ws;                  // [BT,256] fp32 state
    float* kacc = x + (size_t)BT * 256;          // [BT,256] fp32 RK4 accumulator
    _Float16* xsH  = (_Float16*)(kacc + (size_t)BT * 256);
    _Float16* xsL  = xsH  + (size_t)BT * 256;
    _Float16* FH   = xsL  + (size_t)BT * 256;
    _Float16* FL   = FH   + (size_t)BT * 256;
    _Float16* Qhi  = FL   + (size_t)BT * 256;
    _Float16* Qlo  = Qhi  + HSZ;
    _Float16* Khi  = Qlo  + HSZ;
    _Float16* Klo  = Khi  + HSZ;
    _Float16* KtrH = Klo  + HSZ;
    _Float16* KtrL = KtrH + HSZ;
    _Float16* WqkH = KtrL + HSZ;
    _Float16* WqkL = WqkH + (size_t)512 * 256;
    _Float16* WoutH= WqkL + (size_t)512 * 256;
    _Float16* WoutL= WoutH + (size_t)256 * 256;

    split_weights<<<192, 256, 0, stream>>>(Wqk, Wout, WqkH, WqkL, WoutH, WoutL);

    for (int step = 0; step < 4; ++step) {
        l2norm_rows<<<BT / 4, 256, 0, stream>>>(step == 0 ? z : x, x, xsH, xsL);
        for (int s = 0; s < 4; ++s) {
            gemm_mfma<<<dim3(BT / 128, 8), 256, 0, stream>>>(
                xsH, xsL, WqkH, WqkL,
                nullptr, nullptr, nullptr, nullptr, nullptr, nullptr, nullptr,
                Qhi, Qlo, Khi, Klo, KtrH, KtrL, -1);
            kuramoto_attn<<<dim3(TT / 128, NH, NB), 256, 0, stream>>>(
                Qhi, Qlo, Khi, Klo, KtrH, KtrL, FH, FL);
            gemm_mfma<<<dim3(BT / 128, 4), 256, 0, stream>>>(
                FH, FL, WoutH, WoutL,
                omega, bout, x, kacc, xsH, xsL, x,
                nullptr, nullptr, nullptr, nullptr, nullptr, nullptr, s);
        }
    }
    l2norm_rows<<<BT / 4, 256, 0, stream>>>(x, (float*)d_out, nullptr, nullptr);
}

// Round 6
// 2584.603 us; speedup vs baseline: 1.3718x; 1.3718x over previous
//
#include <hip/hip_runtime.h>
#include <cmath>

#define NB 4
#define TT 2048
#define DD 256
#define NH 4
#define BT (NB*TT)   // 8192 rows

static constexpr float DT_ = 0.25f;

typedef _Float16 f16x8 __attribute__((ext_vector_type(8)));
typedef _Float16 f16x4 __attribute__((ext_vector_type(4)));
typedef float    f32x4 __attribute__((ext_vector_type(4)));

static constexpr size_t HSZ = (size_t)NB * NH * TT * 64;   // per split Q/K array: 2M halves

// ---------------- split W into fp16 hi/lo (runs once per launch) ----------------
__global__ __launch_bounds__(256)
void split_weights(const float* __restrict__ Wqk, const float* __restrict__ Wout,
                   _Float16* __restrict__ WqkH, _Float16* __restrict__ WqkL,
                   _Float16* __restrict__ WoutH, _Float16* __restrict__ WoutL)
{
    const int idx = blockIdx.x * 256 + threadIdx.x;   // float4 group index
    const float4 v = (idx < 32768) ? ((const float4*)Wqk)[idx]
                                   : ((const float4*)Wout)[idx - 32768];
    f16x4 h, l;
    h[0]=(_Float16)v.x; l[0]=(_Float16)(v.x-(float)h[0]);
    h[1]=(_Float16)v.y; l[1]=(_Float16)(v.y-(float)h[1]);
    h[2]=(_Float16)v.z; l[2]=(_Float16)(v.z-(float)h[2]);
    h[3]=(_Float16)v.w; l[3]=(_Float16)(v.w-(float)h[3]);
    if (idx < 32768) { ((f16x4*)WqkH)[idx] = h; ((f16x4*)WqkL)[idx] = l; }
    else { ((f16x4*)WoutH)[idx-32768] = h; ((f16x4*)WoutL)[idx-32768] = l; }
}

// ---------------- row-wise l2 norm over D=256; optional fp16 split emit ----------------
__global__ __launch_bounds__(256)
void l2norm_rows(const float* __restrict__ src, float* __restrict__ dst,
                 _Float16* __restrict__ dstH, _Float16* __restrict__ dstL) {
    const int wave = threadIdx.x >> 6;
    const int lane = threadIdx.x & 63;
    const size_t row = (size_t)blockIdx.x * 4 + wave;
    float4 v = ((const float4*)(src + row * DD))[lane];
    float ss = v.x*v.x + v.y*v.y + v.z*v.z + v.w*v.w;
    #pragma unroll
    for (int off = 32; off; off >>= 1) ss += __shfl_xor(ss, off, 64);
    const float inv = 1.0f / fmaxf(sqrtf(ss), 1e-12f);
    v.x *= inv; v.y *= inv; v.z *= inv; v.w *= inv;
    ((float4*)(dst + row * DD))[lane] = v;
    if (dstH != nullptr) {
        f16x4 h, l;
        h[0]=(_Float16)v.x; l[0]=(_Float16)(v.x-(float)h[0]);
        h[1]=(_Float16)v.y; l[1]=(_Float16)(v.y-(float)h[1]);
        h[2]=(_Float16)v.z; l[2]=(_Float16)(v.z-(float)h[2]);
        h[3]=(_Float16)v.w; l[3]=(_Float16)(v.w-(float)h[3]);
        ((f16x4*)(dstH + row * DD))[lane] = h;
        ((f16x4*)(dstL + row * DD))[lane] = l;
    }
}

// ---------------- split-fp16 MFMA GEMM: C = A[M,256] * W[N,256]^T ----------------
// Block 256 thr / 4 waves; tile 128m x 64n; K-loop 4 chunks of 64 via LDS.
// stage -1 : A from AH/AL fp16 splits; epilogue = per-head l2norm + Q/K/Ktr emit.
// stage 0-3: A = F0 + F1 (fp32 partial forces, summed+split during staging);
//            epilogue = f=acc+omega+bout, RK4 update.
__global__ __launch_bounds__(256)
void gemm_mfma(const _Float16* __restrict__ AH, const _Float16* __restrict__ AL,
               const float* __restrict__ F0, const float* __restrict__ F1,
               const _Float16* __restrict__ BH, const _Float16* __restrict__ BL,
               const float* __restrict__ omega, const float* __restrict__ bout,
               const float* __restrict__ xin, float* __restrict__ kacc,
               _Float16* __restrict__ xsH, _Float16* __restrict__ xsL,
               float* __restrict__ xout,
               _Float16* __restrict__ Qhi, _Float16* __restrict__ Qlo,
               _Float16* __restrict__ Khi, _Float16* __restrict__ Klo,
               _Float16* __restrict__ KtrH, _Float16* __restrict__ KtrL,
               int stage)
{
    __shared__ _Float16 Ah[128 * 72];
    __shared__ _Float16 Al[128 * 72];
    __shared__ _Float16 Bh[64 * 72];
    __shared__ _Float16 Bl[64 * 72];
    const int m0 = blockIdx.x * 128, n0 = blockIdx.y * 64;
    const int t  = threadIdx.x;
    const int w  = t >> 6;
    const int l  = t & 63;
    const int lr = l & 15;
    const int lq = l >> 4;

    f32x4 acc[2][4];
    #pragma unroll
    for (int s = 0; s < 2; ++s)
        #pragma unroll
        for (int nt = 0; nt < 4; ++nt) acc[s][nt] = (f32x4){0.f,0.f,0.f,0.f};

    for (int kc = 0; kc < 4; ++kc) {
        const int k0 = kc * 64;
        __syncthreads();
        if (stage < 0) {
            #pragma unroll
            for (int s2 = 0; s2 < 4; ++s2) {
                const int idx = t + 256 * s2;
                const int r = idx >> 3, c8 = (idx & 7) * 8;
                *(uint4*)&Ah[r * 72 + c8] = *(const uint4*)(AH + (size_t)(m0 + r) * 256 + k0 + c8);
                *(uint4*)&Al[r * 72 + c8] = *(const uint4*)(AL + (size_t)(m0 + r) * 256 + k0 + c8);
            }
        } else {
            #pragma unroll
            for (int s2 = 0; s2 < 4; ++s2) {
                const int idx = t + 256 * s2;
                const int r = idx >> 3, c8 = (idx & 7) * 8;
                const size_t go = (size_t)(m0 + r) * 256 + k0 + c8;
                const float4 a0 = *(const float4*)(F0 + go);
                const float4 a1 = *(const float4*)(F0 + go + 4);
                const float4 b0 = *(const float4*)(F1 + go);
                const float4 b1 = *(const float4*)(F1 + go + 4);
                const float sv[8] = {a0.x+b0.x, a0.y+b0.y, a0.z+b0.z, a0.w+b0.w,
                                     a1.x+b1.x, a1.y+b1.y, a1.z+b1.z, a1.w+b1.w};
                f16x8 hv, lv;
                #pragma unroll
                for (int e = 0; e < 8; ++e) {
                    hv[e] = (_Float16)sv[e];
                    lv[e] = (_Float16)(sv[e] - (float)hv[e]);
                }
                *(f16x8*)&Ah[r * 72 + c8] = hv;
                *(f16x8*)&Al[r * 72 + c8] = lv;
            }
        }
        #pragma unroll
        for (int s2 = 0; s2 < 2; ++s2) {
            const int idx = t + 256 * s2;
            const int r = idx >> 3, c8 = (idx & 7) * 8;
            *(uint4*)&Bh[r * 72 + c8] = *(const uint4*)(BH + (size_t)(n0 + r) * 256 + k0 + c8);
            *(uint4*)&Bl[r * 72 + c8] = *(const uint4*)(BL + (size_t)(n0 + r) * 256 + k0 + c8);
        }
        __syncthreads();
        #pragma unroll
        for (int c = 0; c < 2; ++c) {
            f16x8 ah[2], al[2], bh[4], bl[4];
            #pragma unroll
            for (int s = 0; s < 2; ++s) {
                ah[s] = *(const f16x8*)&Ah[(32*w + 16*s + lr) * 72 + 32*c + 8*lq];
                al[s] = *(const f16x8*)&Al[(32*w + 16*s + lr) * 72 + 32*c + 8*lq];
            }
            #pragma unroll
            for (int nt = 0; nt < 4; ++nt) {
                bh[nt] = *(const f16x8*)&Bh[(16*nt + lr) * 72 + 32*c + 8*lq];
                bl[nt] = *(const f16x8*)&Bl[(16*nt + lr) * 72 + 32*c + 8*lq];
            }
            #pragma unroll
            for (int s = 0; s < 2; ++s)
                #pragma unroll
                for (int nt = 0; nt < 4; ++nt) {
                    acc[s][nt] = __builtin_amdgcn_mfma_f32_16x16x32_f16(ah[s], bh[nt], acc[s][nt], 0, 0, 0);
                    acc[s][nt] = __builtin_amdgcn_mfma_f32_16x16x32_f16(ah[s], bl[nt], acc[s][nt], 0, 0, 0);
                    acc[s][nt] = __builtin_amdgcn_mfma_f32_16x16x32_f16(al[s], bh[nt], acc[s][nt], 0, 0, 0);
                }
        }
    }

    if (stage < 0) {
        float ss[2][4];
        #pragma unroll
        for (int s = 0; s < 2; ++s)
            #pragma unroll
            for (int r = 0; r < 4; ++r) {
                float v = 0.f;
                #pragma unroll
                for (int nt = 0; nt < 4; ++nt) v += acc[s][nt][r] * acc[s][nt][r];
                ss[s][r] = v;
            }
        #pragma unroll
        for (int off = 1; off < 16; off <<= 1)
            #pragma unroll
            for (int s = 0; s < 2; ++s)
                #pragma unroll
                for (int r = 0; r < 4; ++r)
                    ss[s][r] += __shfl_xor(ss[s][r], off, 64);
        const int  b    = m0 >> 11;
        const int  h    = (n0 >> 6) & 3;
        const bool is_k = (n0 >= 256);
        const size_t bhi = (size_t)b * NH + h;
        _Float16* dhi = (is_k ? Khi : Qhi) + bhi * (size_t)TT * 64;
        _Float16* dlo = (is_k ? Klo : Qlo) + bhi * (size_t)TT * 64;
        const int mloc = m0 & (TT - 1);
        #pragma unroll
        for (int s = 0; s < 2; ++s) {
            const int r0 = 32*w + 16*s + 4*lq;
            float inv[4];
            #pragma unroll
            for (int r = 0; r < 4; ++r) inv[r] = 1.0f / fmaxf(sqrtf(ss[s][r]), 1e-12f);
            #pragma unroll
            for (int nt = 0; nt < 4; ++nt) {
                const int d = 16*nt + lr;
                f16x4 hv, lv;
                #pragma unroll
                for (int r = 0; r < 4; ++r) {
                    const float val = acc[s][nt][r] * inv[r];
                    hv[r] = (_Float16)val;
                    lv[r] = (_Float16)(val - (float)hv[r]);
                    dhi[(size_t)(mloc + r0 + r) * 64 + d] = hv[r];
                    dlo[(size_t)(mloc + r0 + r) * 64 + d] = lv[r];
                }
                if (is_k) {
                    const size_t tb = bhi * (size_t)64 * TT + (size_t)d * TT + mloc + r0;
                    *(f16x4*)(KtrH + tb) = hv;
                    *(f16x4*)(KtrL + tb) = lv;
                }
            }
        }
    } else {
        #pragma unroll
        for (int s = 0; s < 2; ++s) {
            const int row0 = m0 + 32*w + 16*s + 4*lq;
            #pragma unroll
            for (int nt = 0; nt < 4; ++nt) {
                const int col = n0 + 16*nt + lr;
                const float ob = omega[col] + bout[col];
                #pragma unroll
                for (int r = 0; r < 4; ++r) {
                    const size_t off = (size_t)(row0 + r) * 256 + col;
                    const float f = acc[s][nt][r] + ob;
                    if (stage == 0) {
                        kacc[off] = f;
                        const float xv = xin[off] + 0.125f * f;
                        const _Float16 xh = (_Float16)xv;
                        xsH[off] = xh;
                        xsL[off] = (_Float16)(xv - (float)xh);
                    } else if (stage < 3) {
                        kacc[off] += 2.0f * f;
                        const float c = (stage == 1) ? 0.125f : 0.25f;
                        const float xv = xin[off] + c * f;
                        const _Float16 xh = (_Float16)xv;
                        xsH[off] = xh;
                        xsL[off] = (_Float16)(xv - (float)xh);
                    } else {
                        xout[off] = xin[off] + (DT_ / 6.0f) * (kacc[off] + f);
                    }
                }
            }
        }
    }
}

// unpack interleaved (hi,lo) dword pairs -> hi-frag / lo-frag halves (verified R5)
__device__ inline void unpack_hl(const uint4 a, const uint4 b, f16x8& hi, f16x8& lo) {
    union { unsigned int u[4]; f16x8 v; } H, L;
    H.u[0] = __builtin_amdgcn_perm(a.y, a.x, 0x05040100u);
    L.u[0] = __builtin_amdgcn_perm(a.y, a.x, 0x07060302u);
    H.u[1] = __builtin_amdgcn_perm(a.w, a.z, 0x05040100u);
    L.u[1] = __builtin_amdgcn_perm(a.w, a.z, 0x07060302u);
    H.u[2] = __builtin_amdgcn_perm(b.y, b.x, 0x05040100u);
    L.u[2] = __builtin_amdgcn_perm(b.y, b.x, 0x07060302u);
    H.u[3] = __builtin_amdgcn_perm(b.w, b.z, 0x05040100u);
    L.u[3] = __builtin_amdgcn_perm(b.w, b.z, 0x07060302u);
    hi = H.v; lo = L.v;
}

// ---------------- F_partial = sin(Q K^T) K over a 1024-j half ----------------
// grid (TT/128, 2 j-halves, NB*NH); 512 blocks -> 2 blocks/CU (the R5 fix).
// 32 i-rows/wave, B-frags amortized over 2 subtiles, packed-P staging,
// register double-buffer of K-tile global loads. Partial F written fp32.
__global__ __launch_bounds__(256)
void kuramoto_attn(const _Float16* __restrict__ Qhi, const _Float16* __restrict__ Qlo,
                   const _Float16* __restrict__ Khi, const _Float16* __restrict__ Klo,
                   const _Float16* __restrict__ KtrH, const _Float16* __restrict__ KtrL,
                   float* __restrict__ Fp)
{
    __shared__ _Float16 KjH[64 * 72];
    __shared__ _Float16 KjL[64 * 72];
    __shared__ _Float16 KdH[64 * 72];
    __shared__ _Float16 KdL[64 * 72];
    __shared__ unsigned int Pw[4][16 * 68];
    const int bh = blockIdx.z;                     // b*NH + h
    const int b  = bh >> 2, h = bh & 3;
    const size_t base  = (size_t)bh * TT * 64;
    const size_t tbase = (size_t)bh * 64 * TT;
    const int jh0 = blockIdx.y * 1024;
    float* Fout = Fp + (size_t)blockIdx.y * BT * 256;
    const int t = threadIdx.x;
    const int w = t >> 6;
    const int l = t & 63;
    const int lr = l & 15;
    const int lq = l >> 4;
    const int i0 = blockIdx.x * 128 + w * 32;

    f16x8 qh[2][2], ql[2][2];
    #pragma unroll
    for (int s = 0; s < 2; ++s) {
        const size_t qoff = base + (size_t)(i0 + 16*s + lr) * 64 + lq * 8;
        qh[s][0] = *(const f16x8*)(Qhi + qoff);
        qh[s][1] = *(const f16x8*)(Qhi + qoff + 32);
        ql[s][0] = *(const f16x8*)(Qlo + qoff);
        ql[s][1] = *(const f16x8*)(Qlo + qoff + 32);
    }

    f32x4 Facc[2][4];
    #pragma unroll
    for (int s = 0; s < 2; ++s)
        #pragma unroll
        for (int nt = 0; nt < 4; ++nt) Facc[s][nt] = (f32x4){0.f, 0.f, 0.f, 0.f};

    const int sr = t >> 3;
    const int so = (t & 7) * 8;

    uint4 g[8];
    {
        g[0] = *(const uint4*)(Khi + base + (size_t)(jh0 + sr) * 64 + so);
        g[1] = *(const uint4*)(Khi + base + (size_t)(jh0 + sr + 32) * 64 + so);
        g[2] = *(const uint4*)(Klo + base + (size_t)(jh0 + sr) * 64 + so);
        g[3] = *(const uint4*)(Klo + base + (size_t)(jh0 + sr + 32) * 64 + so);
        g[4] = *(const uint4*)(KtrH + tbase + (size_t)sr * TT + jh0 + so);
        g[5] = *(const uint4*)(KtrH + tbase + (size_t)(sr + 32) * TT + jh0 + so);
        g[6] = *(const uint4*)(KtrL + tbase + (size_t)sr * TT + jh0 + so);
        g[7] = *(const uint4*)(KtrL + tbase + (size_t)(sr + 32) * TT + jh0 + so);
    }

    for (int j0 = jh0; j0 < jh0 + 1024; j0 += 64) {
        __syncthreads();
        *(uint4*)&KjH[sr * 72 + so]        = g[0];
        *(uint4*)&KjH[(sr + 32) * 72 + so] = g[1];
        *(uint4*)&KjL[sr * 72 + so]        = g[2];
        *(uint4*)&KjL[(sr + 32) * 72 + so] = g[3];
        *(uint4*)&KdH[sr * 72 + so]        = g[4];
        *(uint4*)&KdH[(sr + 32) * 72 + so] = g[5];
        *(uint4*)&KdL[sr * 72 + so]        = g[6];
        *(uint4*)&KdL[(sr + 32) * 72 + so] = g[7];
        __syncthreads();
        {   // prefetch next tile (wrapped within the half) under compute
            const int jn = jh0 + ((j0 - jh0 + 64) & 1023);
            g[0] = *(const uint4*)(Khi + base + (size_t)(jn + sr) * 64 + so);
            g[1] = *(const uint4*)(Khi + base + (size_t)(jn + sr + 32) * 64 + so);
            g[2] = *(const uint4*)(Klo + base + (size_t)(jn + sr) * 64 + so);
            g[3] = *(const uint4*)(Klo + base + (size_t)(jn + sr + 32) * 64 + so);
            g[4] = *(const uint4*)(KtrH + tbase + (size_t)sr * TT + jn + so);
            g[5] = *(const uint4*)(KtrH + tbase + (size_t)(sr + 32) * TT + jn + so);
            g[6] = *(const uint4*)(KtrL + tbase + (size_t)sr * TT + jn + so);
            g[7] = *(const uint4*)(KtrL + tbase + (size_t)(sr + 32) * TT + jn + so);
        }
        // GEMM1: S[s] (16i x 64j) = Q K^T, B-frags shared by both subtiles
        f32x4 S[2][4];
        #pragma unroll
        for (int nt = 0; nt < 4; ++nt) {
            f16x8 bh0 = *(const f16x8*)&KjH[(16*nt + lr) * 72 + lq * 8];
            f16x8 bh1 = *(const f16x8*)&KjH[(16*nt + lr) * 72 + 32 + lq * 8];
            f16x8 bl0 = *(const f16x8*)&KjL[(16*nt + lr) * 72 + lq * 8];
            f16x8 bl1 = *(const f16x8*)&KjL[(16*nt + lr) * 72 + 32 + lq * 8];
            #pragma unroll
            for (int s = 0; s < 2; ++s) {
                f32x4 acc = (f32x4){0.f, 0.f, 0.f, 0.f};
                acc = __builtin_amdgcn_mfma_f32_16x16x32_f16(qh[s][0], bh0, acc, 0, 0, 0);
                acc = __builtin_amdgcn_mfma_f32_16x16x32_f16(qh[s][1], bh1, acc, 0, 0, 0);
                acc = __builtin_amdgcn_mfma_f32_16x16x32_f16(qh[s][0], bl0, acc, 0, 0, 0);
                acc = __builtin_amdgcn_mfma_f32_16x16x32_f16(qh[s][1], bl1, acc, 0, 0, 0);
                acc = __builtin_amdgcn_mfma_f32_16x16x32_f16(ql[s][0], bh0, acc, 0, 0, 0);
                acc = __builtin_amdgcn_mfma_f32_16x16x32_f16(ql[s][1], bh1, acc, 0, 0, 0);
                S[s][nt] = acc;
            }
        }
        // sin -> packed (hi,lo) -> per-wave LDS round trip -> A-frags
        f16x8 ph[2][2], pl[2][2];
        #pragma unroll
        for (int s = 0; s < 2; ++s) {
            #pragma unroll
            for (int nt = 0; nt < 4; ++nt)
                #pragma unroll
                for (int r = 0; r < 4; ++r) {
                    const float p = __sinf(S[s][nt][r]);
                    const _Float16 hi = (_Float16)p;
                    const _Float16 lo = (_Float16)(p - (float)hi);
                    const unsigned int pk =
                        ((unsigned int)__builtin_bit_cast(unsigned short, lo) << 16)
                        | (unsigned int)__builtin_bit_cast(unsigned short, hi);
                    Pw[w][(4*lq + r) * 68 + 16*nt + lr] = pk;
                }
            #pragma unroll
            for (int c = 0; c < 2; ++c) {
                const uint4 a  = *(const uint4*)&Pw[w][lr * 68 + c * 32 + lq * 8];
                const uint4 bq = *(const uint4*)&Pw[w][lr * 68 + c * 32 + lq * 8 + 4];
                unpack_hl(a, bq, ph[s][c], pl[s][c]);
            }
        }
        // GEMM2: F[s] += P K, B-frags shared by both subtiles
        #pragma unroll
        for (int nt = 0; nt < 4; ++nt) {
            f16x8 kh0 = *(const f16x8*)&KdH[(16*nt + lr) * 72 + lq * 8];
            f16x8 kh1 = *(const f16x8*)&KdH[(16*nt + lr) * 72 + 32 + lq * 8];
            f16x8 kl0 = *(const f16x8*)&KdL[(16*nt + lr) * 72 + lq * 8];
            f16x8 kl1 = *(const f16x8*)&KdL[(16*nt + lr) * 72 + 32 + lq * 8];
            #pragma unroll
            for (int s = 0; s < 2; ++s) {
                Facc[s][nt] = __builtin_amdgcn_mfma_f32_16x16x32_f16(ph[s][0], kh0, Facc[s][nt], 0, 0, 0);
                Facc[s][nt] = __builtin_amdgcn_mfma_f32_16x16x32_f16(ph[s][1], kh1, Facc[s][nt], 0, 0, 0);
                Facc[s][nt] = __builtin_amdgcn_mfma_f32_16x16x32_f16(ph[s][0], kl0, Facc[s][nt], 0, 0, 0);
                Facc[s][nt] = __builtin_amdgcn_mfma_f32_16x16x32_f16(ph[s][1], kl1, Facc[s][nt], 0, 0, 0);
                Facc[s][nt] = __builtin_amdgcn_mfma_f32_16x16x32_f16(pl[s][0], kh0, Facc[s][nt], 0, 0, 0);
                Facc[s][nt] = __builtin_amdgcn_mfma_f32_16x16x32_f16(pl[s][1], kh1, Facc[s][nt], 0, 0, 0);
            }
        }
    }
    // write partial F fp32: row = i0 + 16s + 4lq + r, col = h*64 + 16nt + lr
    #pragma unroll
    for (int s = 0; s < 2; ++s) {
        float* fo = Fout + ((size_t)b * TT + i0 + 16*s + 4*lq) * 256 + h * 64 + lr;
        #pragma unroll
        for (int nt = 0; nt < 4; ++nt)
            #pragma unroll
            for (int r = 0; r < 4; ++r)
                fo[(size_t)r * 256 + nt * 16] = Facc[s][nt][r];
    }
}

extern "C" void kernel_launch(void* const* d_in, const int* in_sizes, int n_in,
                              void* d_out, int out_size, void* d_ws, size_t ws_size,
                              hipStream_t stream) {
    const float* z     = (const float*)d_in[0];
    const float* omega = (const float*)d_in[1];
    const float* Wqk   = (const float*)d_in[2];
    const float* Wout  = (const float*)d_in[3];
    const float* bout  = (const float*)d_in[4];

    float* x    = (float*)d_ws;                  // [BT,256] fp32 state
    float* kacc = x + (size_t)BT * 256;          // [BT,256] fp32 RK4 accumulator
    float* Fp   = kacc + (size_t)BT * 256;       // [2][BT,256] fp32 partial forces
    _Float16* xsH  = (_Float16*)(Fp + (size_t)2 * BT * 256);
    _Float16* xsL  = xsH  + (size_t)BT * 256;
    _Float16* Qhi  = xsL  + (size_t)BT * 256;
    _Float16* Qlo  = Qhi  + HSZ;
    _Float16* Khi  = Qlo  + HSZ;
    _Float16* Klo  = Khi  + HSZ;
    _Float16* KtrH = Klo  + HSZ;
    _Float16* KtrL = KtrH + HSZ;
    _Float16* WqkH = KtrL + HSZ;
    _Float16* WqkL = WqkH + (size_t)512 * 256;
    _Float16* WoutH= WqkL + (size_t)512 * 256;
    _Float16* WoutL= WoutH + (size_t)256 * 256;

    split_weights<<<192, 256, 0, stream>>>(Wqk, Wout, WqkH, WqkL, WoutH, WoutL);

    for (int step = 0; step < 4; ++step) {
        l2norm_rows<<<BT / 4, 256, 0, stream>>>(step == 0 ? z : x, x, xsH, xsL);
        for (int s = 0; s < 4; ++s) {
            gemm_mfma<<<dim3(BT / 128, 8), 256, 0, stream>>>(
                xsH, xsL, nullptr, nullptr, WqkH, WqkL,
                nullptr, nullptr, nullptr, nullptr, nullptr, nullptr, nullptr,
                Qhi, Qlo, Khi, Klo, KtrH, KtrL, -1);
            kuramoto_attn<<<dim3(TT / 128, 2, NB * NH), 256, 0, stream>>>(
                Qhi, Qlo, Khi, Klo, KtrH, KtrL, Fp);
            gemm_mfma<<<dim3(BT / 128, 4), 256, 0, stream>>>(
                nullptr, nullptr, Fp, Fp + (size_t)BT * 256, WoutH, WoutL,
                omega, bout, x, kacc, xsH, xsL, x,
                nullptr, nullptr, nullptr, nullptr, nullptr, nullptr, s);
        }
    }
    l2norm_rows<<<BT / 4, 256, 0, stream>>>(x, (float*)d_out, nullptr, nullptr);
}

// Round 7
// 1919.962 us; speedup vs baseline: 1.8466x; 1.3462x over previous
//
#include <hip/hip_runtime.h>
#include <cmath>

#define NB 4
#define TT 2048
#define DD 256
#define NH 4
#define BT (NB*TT)   // 8192 rows

static constexpr float DT_ = 0.25f;

typedef _Float16 f16x8 __attribute__((ext_vector_type(8)));
typedef _Float16 f16x4 __attribute__((ext_vector_type(4)));
typedef float    f32x4 __attribute__((ext_vector_type(4)));

static constexpr size_t HSZ = (size_t)NB * NH * TT * 64;   // per split Q/K array: 2M halves

// ---------------- split W into fp16 hi/lo (runs once per launch) ----------------
__global__ __launch_bounds__(256)
void split_weights(const float* __restrict__ Wqk, const float* __restrict__ Wout,
                   _Float16* __restrict__ WqkH, _Float16* __restrict__ WqkL,
                   _Float16* __restrict__ WoutH, _Float16* __restrict__ WoutL)
{
    const int idx = blockIdx.x * 256 + threadIdx.x;   // float4 group index
    const float4 v = (idx < 32768) ? ((const float4*)Wqk)[idx]
                                   : ((const float4*)Wout)[idx - 32768];
    f16x4 h, l;
    h[0]=(_Float16)v.x; l[0]=(_Float16)(v.x-(float)h[0]);
    h[1]=(_Float16)v.y; l[1]=(_Float16)(v.y-(float)h[1]);
    h[2]=(_Float16)v.z; l[2]=(_Float16)(v.z-(float)h[2]);
    h[3]=(_Float16)v.w; l[3]=(_Float16)(v.w-(float)h[3]);
    if (idx < 32768) { ((f16x4*)WqkH)[idx] = h; ((f16x4*)WqkL)[idx] = l; }
    else { ((f16x4*)WoutH)[idx-32768] = h; ((f16x4*)WoutL)[idx-32768] = l; }
}

// ---------------- row-wise l2 norm over D=256; optional fp16 split emit ----------------
__global__ __launch_bounds__(256)
void l2norm_rows(const float* __restrict__ src, float* __restrict__ dst,
                 _Float16* __restrict__ dstH, _Float16* __restrict__ dstL) {
    const int wave = threadIdx.x >> 6;
    const int lane = threadIdx.x & 63;
    const size_t row = (size_t)blockIdx.x * 4 + wave;
    float4 v = ((const float4*)(src + row * DD))[lane];
    float ss = v.x*v.x + v.y*v.y + v.z*v.z + v.w*v.w;
    #pragma unroll
    for (int off = 32; off; off >>= 1) ss += __shfl_xor(ss, off, 64);
    const float inv = 1.0f / fmaxf(sqrtf(ss), 1e-12f);
    v.x *= inv; v.y *= inv; v.z *= inv; v.w *= inv;
    ((float4*)(dst + row * DD))[lane] = v;
    if (dstH != nullptr) {
        f16x4 h, l;
        h[0]=(_Float16)v.x; l[0]=(_Float16)(v.x-(float)h[0]);
        h[1]=(_Float16)v.y; l[1]=(_Float16)(v.y-(float)h[1]);
        h[2]=(_Float16)v.z; l[2]=(_Float16)(v.z-(float)h[2]);
        h[3]=(_Float16)v.w; l[3]=(_Float16)(v.w-(float)h[3]);
        ((f16x4*)(dstH + row * DD))[lane] = h;
        ((f16x4*)(dstL + row * DD))[lane] = l;
    }
}

// ---------------- split-fp16 MFMA GEMM: C = A[M,256] * W[N,256]^T ----------------
// (unchanged from R6 — passing) Block 256 thr / 4 waves; tile 128m x 64n.
__global__ __launch_bounds__(256)
void gemm_mfma(const _Float16* __restrict__ AH, const _Float16* __restrict__ AL,
               const float* __restrict__ F0, const float* __restrict__ F1,
               const _Float16* __restrict__ BH, const _Float16* __restrict__ BL,
               const float* __restrict__ omega, const float* __restrict__ bout,
               const float* __restrict__ xin, float* __restrict__ kacc,
               _Float16* __restrict__ xsH, _Float16* __restrict__ xsL,
               float* __restrict__ xout,
               _Float16* __restrict__ Qhi, _Float16* __restrict__ Qlo,
               _Float16* __restrict__ Khi, _Float16* __restrict__ Klo,
               _Float16* __restrict__ KtrH, _Float16* __restrict__ KtrL,
               int stage)
{
    __shared__ _Float16 Ah[128 * 72];
    __shared__ _Float16 Al[128 * 72];
    __shared__ _Float16 Bh[64 * 72];
    __shared__ _Float16 Bl[64 * 72];
    const int m0 = blockIdx.x * 128, n0 = blockIdx.y * 64;
    const int t  = threadIdx.x;
    const int w  = t >> 6;
    const int l  = t & 63;
    const int lr = l & 15;
    const int lq = l >> 4;

    f32x4 acc[2][4];
    #pragma unroll
    for (int s = 0; s < 2; ++s)
        #pragma unroll
        for (int nt = 0; nt < 4; ++nt) acc[s][nt] = (f32x4){0.f,0.f,0.f,0.f};

    for (int kc = 0; kc < 4; ++kc) {
        const int k0 = kc * 64;
        __syncthreads();
        if (stage < 0) {
            #pragma unroll
            for (int s2 = 0; s2 < 4; ++s2) {
                const int idx = t + 256 * s2;
                const int r = idx >> 3, c8 = (idx & 7) * 8;
                *(uint4*)&Ah[r * 72 + c8] = *(const uint4*)(AH + (size_t)(m0 + r) * 256 + k0 + c8);
                *(uint4*)&Al[r * 72 + c8] = *(const uint4*)(AL + (size_t)(m0 + r) * 256 + k0 + c8);
            }
        } else {
            #pragma unroll
            for (int s2 = 0; s2 < 4; ++s2) {
                const int idx = t + 256 * s2;
                const int r = idx >> 3, c8 = (idx & 7) * 8;
                const size_t go = (size_t)(m0 + r) * 256 + k0 + c8;
                const float4 a0 = *(const float4*)(F0 + go);
                const float4 a1 = *(const float4*)(F0 + go + 4);
                const float4 b0 = *(const float4*)(F1 + go);
                const float4 b1 = *(const float4*)(F1 + go + 4);
                const float sv[8] = {a0.x+b0.x, a0.y+b0.y, a0.z+b0.z, a0.w+b0.w,
                                     a1.x+b1.x, a1.y+b1.y, a1.z+b1.z, a1.w+b1.w};
                f16x8 hv, lv;
                #pragma unroll
                for (int e = 0; e < 8; ++e) {
                    hv[e] = (_Float16)sv[e];
                    lv[e] = (_Float16)(sv[e] - (float)hv[e]);
                }
                *(f16x8*)&Ah[r * 72 + c8] = hv;
                *(f16x8*)&Al[r * 72 + c8] = lv;
            }
        }
        #pragma unroll
        for (int s2 = 0; s2 < 2; ++s2) {
            const int idx = t + 256 * s2;
            const int r = idx >> 3, c8 = (idx & 7) * 8;
            *(uint4*)&Bh[r * 72 + c8] = *(const uint4*)(BH + (size_t)(n0 + r) * 256 + k0 + c8);
            *(uint4*)&Bl[r * 72 + c8] = *(const uint4*)(BL + (size_t)(n0 + r) * 256 + k0 + c8);
        }
        __syncthreads();
        #pragma unroll
        for (int c = 0; c < 2; ++c) {
            f16x8 ah[2], al[2], bh[4], bl[4];
            #pragma unroll
            for (int s = 0; s < 2; ++s) {
                ah[s] = *(const f16x8*)&Ah[(32*w + 16*s + lr) * 72 + 32*c + 8*lq];
                al[s] = *(const f16x8*)&Al[(32*w + 16*s + lr) * 72 + 32*c + 8*lq];
            }
            #pragma unroll
            for (int nt = 0; nt < 4; ++nt) {
                bh[nt] = *(const f16x8*)&Bh[(16*nt + lr) * 72 + 32*c + 8*lq];
                bl[nt] = *(const f16x8*)&Bl[(16*nt + lr) * 72 + 32*c + 8*lq];
            }
            #pragma unroll
            for (int s = 0; s < 2; ++s)
                #pragma unroll
                for (int nt = 0; nt < 4; ++nt) {
                    acc[s][nt] = __builtin_amdgcn_mfma_f32_16x16x32_f16(ah[s], bh[nt], acc[s][nt], 0, 0, 0);
                    acc[s][nt] = __builtin_amdgcn_mfma_f32_16x16x32_f16(ah[s], bl[nt], acc[s][nt], 0, 0, 0);
                    acc[s][nt] = __builtin_amdgcn_mfma_f32_16x16x32_f16(al[s], bh[nt], acc[s][nt], 0, 0, 0);
                }
        }
    }

    if (stage < 0) {
        float ss[2][4];
        #pragma unroll
        for (int s = 0; s < 2; ++s)
            #pragma unroll
            for (int r = 0; r < 4; ++r) {
                float v = 0.f;
                #pragma unroll
                for (int nt = 0; nt < 4; ++nt) v += acc[s][nt][r] * acc[s][nt][r];
                ss[s][r] = v;
            }
        #pragma unroll
        for (int off = 1; off < 16; off <<= 1)
            #pragma unroll
            for (int s = 0; s < 2; ++s)
                #pragma unroll
                for (int r = 0; r < 4; ++r)
                    ss[s][r] += __shfl_xor(ss[s][r], off, 64);
        const int  b    = m0 >> 11;
        const int  h    = (n0 >> 6) & 3;
        const bool is_k = (n0 >= 256);
        const size_t bhi = (size_t)b * NH + h;
        _Float16* dhi = (is_k ? Khi : Qhi) + bhi * (size_t)TT * 64;
        _Float16* dlo = (is_k ? Klo : Qlo) + bhi * (size_t)TT * 64;
        const int mloc = m0 & (TT - 1);
        #pragma unroll
        for (int s = 0; s < 2; ++s) {
            const int r0 = 32*w + 16*s + 4*lq;
            float inv[4];
            #pragma unroll
            for (int r = 0; r < 4; ++r) inv[r] = 1.0f / fmaxf(sqrtf(ss[s][r]), 1e-12f);
            #pragma unroll
            for (int nt = 0; nt < 4; ++nt) {
                const int d = 16*nt + lr;
                f16x4 hv, lv;
                #pragma unroll
                for (int r = 0; r < 4; ++r) {
                    const float val = acc[s][nt][r] * inv[r];
                    hv[r] = (_Float16)val;
                    lv[r] = (_Float16)(val - (float)hv[r]);
                    dhi[(size_t)(mloc + r0 + r) * 64 + d] = hv[r];
                    dlo[(size_t)(mloc + r0 + r) * 64 + d] = lv[r];
                }
                if (is_k) {
                    const size_t tb = bhi * (size_t)64 * TT + (size_t)d * TT + mloc + r0;
                    *(f16x4*)(KtrH + tb) = hv;
                    *(f16x4*)(KtrL + tb) = lv;
                }
            }
        }
    } else {
        #pragma unroll
        for (int s = 0; s < 2; ++s) {
            const int row0 = m0 + 32*w + 16*s + 4*lq;
            #pragma unroll
            for (int nt = 0; nt < 4; ++nt) {
                const int col = n0 + 16*nt + lr;
                const float ob = omega[col] + bout[col];
                #pragma unroll
                for (int r = 0; r < 4; ++r) {
                    const size_t off = (size_t)(row0 + r) * 256 + col;
                    const float f = acc[s][nt][r] + ob;
                    if (stage == 0) {
                        kacc[off] = f;
                        const float xv = xin[off] + 0.125f * f;
                        const _Float16 xh = (_Float16)xv;
                        xsH[off] = xh;
                        xsL[off] = (_Float16)(xv - (float)xh);
                    } else if (stage < 3) {
                        kacc[off] += 2.0f * f;
                        const float c = (stage == 1) ? 0.125f : 0.25f;
                        const float xv = xin[off] + c * f;
                        const _Float16 xh = (_Float16)xv;
                        xsH[off] = xh;
                        xsL[off] = (_Float16)(xv - (float)xh);
                    } else {
                        xout[off] = xin[off] + (DT_ / 6.0f) * (kacc[off] + f);
                    }
                }
            }
        }
    }
}

// unpack interleaved (hi,lo) dword pairs -> hi-frag / lo-frag halves (verified R5/R6)
__device__ inline void unpack_hl(const uint4 a, const uint4 b, f16x8& hi, f16x8& lo) {
    union { unsigned int u[4]; f16x8 v; } H, L;
    H.u[0] = __builtin_amdgcn_perm(a.y, a.x, 0x05040100u);
    L.u[0] = __builtin_amdgcn_perm(a.y, a.x, 0x07060302u);
    H.u[1] = __builtin_amdgcn_perm(a.w, a.z, 0x05040100u);
    L.u[1] = __builtin_amdgcn_perm(a.w, a.z, 0x07060302u);
    H.u[2] = __builtin_amdgcn_perm(b.y, b.x, 0x05040100u);
    L.u[2] = __builtin_amdgcn_perm(b.y, b.x, 0x07060302u);
    H.u[3] = __builtin_amdgcn_perm(b.w, b.z, 0x05040100u);
    L.u[3] = __builtin_amdgcn_perm(b.w, b.z, 0x07060302u);
    hi = H.v; lo = L.v;
}

// ---------------- F_partial = sin(Q K^T) K over a 1024-j half ----------------
// grid (TT/128, 2, NB*NH) = 512 blocks -> 2 blocks/CU. 32 i-rows/wave.
// R7: __launch_bounds__(256,2) -> 256 VGPR budget (kills the R6 scratch spills);
// register prefetch g[] removed (32 fewer persistent VGPRs) — the co-resident
// block hides the staging latency (R4-proven).
__global__ __launch_bounds__(256, 2)
void kuramoto_attn(const _Float16* __restrict__ Qhi, const _Float16* __restrict__ Qlo,
                   const _Float16* __restrict__ Khi, const _Float16* __restrict__ Klo,
                   const _Float16* __restrict__ KtrH, const _Float16* __restrict__ KtrL,
                   float* __restrict__ Fp)
{
    __shared__ _Float16 KjH[64 * 72];
    __shared__ _Float16 KjL[64 * 72];
    __shared__ _Float16 KdH[64 * 72];
    __shared__ _Float16 KdL[64 * 72];
    __shared__ unsigned int Pw[4][16 * 68];
    const int bh = blockIdx.z;                     // b*NH + h
    const int b  = bh >> 2, h = bh & 3;
    const size_t base  = (size_t)bh * TT * 64;
    const size_t tbase = (size_t)bh * 64 * TT;
    const int jh0 = blockIdx.y * 1024;
    float* Fout = Fp + (size_t)blockIdx.y * BT * 256;
    const int t = threadIdx.x;
    const int w = t >> 6;
    const int l = t & 63;
    const int lr = l & 15;
    const int lq = l >> 4;
    const int i0 = blockIdx.x * 128 + w * 32;

    f16x8 qh[2][2], ql[2][2];
    #pragma unroll
    for (int s = 0; s < 2; ++s) {
        const size_t qoff = base + (size_t)(i0 + 16*s + lr) * 64 + lq * 8;
        qh[s][0] = *(const f16x8*)(Qhi + qoff);
        qh[s][1] = *(const f16x8*)(Qhi + qoff + 32);
        ql[s][0] = *(const f16x8*)(Qlo + qoff);
        ql[s][1] = *(const f16x8*)(Qlo + qoff + 32);
    }

    f32x4 Facc[2][4];
    #pragma unroll
    for (int s = 0; s < 2; ++s)
        #pragma unroll
        for (int nt = 0; nt < 4; ++nt) Facc[s][nt] = (f32x4){0.f, 0.f, 0.f, 0.f};

    const int sr = t >> 3;
    const int so = (t & 7) * 8;

    for (int j0 = jh0; j0 < jh0 + 1024; j0 += 64) {
        __syncthreads();   // previous tile's LDS reads complete
        {   // direct global -> LDS staging (no persistent prefetch registers)
            *(uint4*)&KjH[sr * 72 + so]        = *(const uint4*)(Khi + base + (size_t)(j0 + sr) * 64 + so);
            *(uint4*)&KjH[(sr + 32) * 72 + so] = *(const uint4*)(Khi + base + (size_t)(j0 + sr + 32) * 64 + so);
            *(uint4*)&KjL[sr * 72 + so]        = *(const uint4*)(Klo + base + (size_t)(j0 + sr) * 64 + so);
            *(uint4*)&KjL[(sr + 32) * 72 + so] = *(const uint4*)(Klo + base + (size_t)(j0 + sr + 32) * 64 + so);
            *(uint4*)&KdH[sr * 72 + so]        = *(const uint4*)(KtrH + tbase + (size_t)sr * TT + j0 + so);
            *(uint4*)&KdH[(sr + 32) * 72 + so] = *(const uint4*)(KtrH + tbase + (size_t)(sr + 32) * TT + j0 + so);
            *(uint4*)&KdL[sr * 72 + so]        = *(const uint4*)(KtrL + tbase + (size_t)sr * TT + j0 + so);
            *(uint4*)&KdL[(sr + 32) * 72 + so] = *(const uint4*)(KtrL + tbase + (size_t)(sr + 32) * TT + j0 + so);
        }
        __syncthreads();
        // GEMM1: S[s] (16i x 64j) = Q K^T, B-frags shared by both subtiles
        f32x4 S[2][4];
        #pragma unroll
        for (int nt = 0; nt < 4; ++nt) {
            f16x8 bh0 = *(const f16x8*)&KjH[(16*nt + lr) * 72 + lq * 8];
            f16x8 bh1 = *(const f16x8*)&KjH[(16*nt + lr) * 72 + 32 + lq * 8];
            f16x8 bl0 = *(const f16x8*)&KjL[(16*nt + lr) * 72 + lq * 8];
            f16x8 bl1 = *(const f16x8*)&KjL[(16*nt + lr) * 72 + 32 + lq * 8];
            #pragma unroll
            for (int s = 0; s < 2; ++s) {
                f32x4 acc = (f32x4){0.f, 0.f, 0.f, 0.f};
                acc = __builtin_amdgcn_mfma_f32_16x16x32_f16(qh[s][0], bh0, acc, 0, 0, 0);
                acc = __builtin_amdgcn_mfma_f32_16x16x32_f16(qh[s][1], bh1, acc, 0, 0, 0);
                acc = __builtin_amdgcn_mfma_f32_16x16x32_f16(qh[s][0], bl0, acc, 0, 0, 0);
                acc = __builtin_amdgcn_mfma_f32_16x16x32_f16(qh[s][1], bl1, acc, 0, 0, 0);
                acc = __builtin_amdgcn_mfma_f32_16x16x32_f16(ql[s][0], bh0, acc, 0, 0, 0);
                acc = __builtin_amdgcn_mfma_f32_16x16x32_f16(ql[s][1], bh1, acc, 0, 0, 0);
                S[s][nt] = acc;
            }
        }
        // sin -> packed (hi,lo) -> per-wave LDS round trip -> A-frags
        f16x8 ph[2][2], pl[2][2];
        #pragma unroll
        for (int s = 0; s < 2; ++s) {
            #pragma unroll
            for (int nt = 0; nt < 4; ++nt)
                #pragma unroll
                for (int r = 0; r < 4; ++r) {
                    const float p = __sinf(S[s][nt][r]);
                    const _Float16 hi = (_Float16)p;
                    const _Float16 lo = (_Float16)(p - (float)hi);
                    const unsigned int pk =
                        ((unsigned int)__builtin_bit_cast(unsigned short, lo) << 16)
                        | (unsigned int)__builtin_bit_cast(unsigned short, hi);
                    Pw[w][(4*lq + r) * 68 + 16*nt + lr] = pk;
                }
            #pragma unroll
            for (int c = 0; c < 2; ++c) {
                const uint4 a  = *(const uint4*)&Pw[w][lr * 68 + c * 32 + lq * 8];
                const uint4 bq = *(const uint4*)&Pw[w][lr * 68 + c * 32 + lq * 8 + 4];
                unpack_hl(a, bq, ph[s][c], pl[s][c]);
            }
        }
        // GEMM2: F[s] += P K, B-frags shared by both subtiles
        #pragma unroll
        for (int nt = 0; nt < 4; ++nt) {
            f16x8 kh0 = *(const f16x8*)&KdH[(16*nt + lr) * 72 + lq * 8];
            f16x8 kh1 = *(const f16x8*)&KdH[(16*nt + lr) * 72 + 32 + lq * 8];
            f16x8 kl0 = *(const f16x8*)&KdL[(16*nt + lr) * 72 + lq * 8];
            f16x8 kl1 = *(const f16x8*)&KdL[(16*nt + lr) * 72 + 32 + lq * 8];
            #pragma unroll
            for (int s = 0; s < 2; ++s) {
                Facc[s][nt] = __builtin_amdgcn_mfma_f32_16x16x32_f16(ph[s][0], kh0, Facc[s][nt], 0, 0, 0);
                Facc[s][nt] = __builtin_amdgcn_mfma_f32_16x16x32_f16(ph[s][1], kh1, Facc[s][nt], 0, 0, 0);
                Facc[s][nt] = __builtin_amdgcn_mfma_f32_16x16x32_f16(ph[s][0], kl0, Facc[s][nt], 0, 0, 0);
                Facc[s][nt] = __builtin_amdgcn_mfma_f32_16x16x32_f16(ph[s][1], kl1, Facc[s][nt], 0, 0, 0);
                Facc[s][nt] = __builtin_amdgcn_mfma_f32_16x16x32_f16(pl[s][0], kh0, Facc[s][nt], 0, 0, 0);
                Facc[s][nt] = __builtin_amdgcn_mfma_f32_16x16x32_f16(pl[s][1], kh1, Facc[s][nt], 0, 0, 0);
            }
        }
    }
    // write partial F fp32: row = i0 + 16s + 4lq + r, col = h*64 + 16nt + lr
    #pragma unroll
    for (int s = 0; s < 2; ++s) {
        float* fo = Fout + ((size_t)b * TT + i0 + 16*s + 4*lq) * 256 + h * 64 + lr;
        #pragma unroll
        for (int nt = 0; nt < 4; ++nt)
            #pragma unroll
            for (int r = 0; r < 4; ++r)
                fo[(size_t)r * 256 + nt * 16] = Facc[s][nt][r];
    }
}

extern "C" void kernel_launch(void* const* d_in, const int* in_sizes, int n_in,
                              void* d_out, int out_size, void* d_ws, size_t ws_size,
                              hipStream_t stream) {
    const float* z     = (const float*)d_in[0];
    const float* omega = (const float*)d_in[1];
    const float* Wqk   = (const float*)d_in[2];
    const float* Wout  = (const float*)d_in[3];
    const float* bout  = (const float*)d_in[4];

    float* x    = (float*)d_ws;                  // [BT,256] fp32 state
    float* kacc = x + (size_t)BT * 256;          // [BT,256] fp32 RK4 accumulator
    float* Fp   = kacc + (size_t)BT * 256;       // [2][BT,256] fp32 partial forces
    _Float16* xsH  = (_Float16*)(Fp + (size_t)2 * BT * 256);
    _Float16* xsL  = xsH  + (size_t)BT * 256;
    _Float16* Qhi  = xsL  + (size_t)BT * 256;
    _Float16* Qlo  = Qhi  + HSZ;
    _Float16* Khi  = Qlo  + HSZ;
    _Float16* Klo  = Khi  + HSZ;
    _Float16* KtrH = Klo  + HSZ;
    _Float16* KtrL = KtrH + HSZ;
    _Float16* WqkH = KtrL + HSZ;
    _Float16* WqkL = WqkH + (size_t)512 * 256;
    _Float16* WoutH= WqkL + (size_t)512 * 256;
    _Float16* WoutL= WoutH + (size_t)256 * 256;

    split_weights<<<192, 256, 0, stream>>>(Wqk, Wout, WqkH, WqkL, WoutH, WoutL);

    for (int step = 0; step < 4; ++step) {
        l2norm_rows<<<BT / 4, 256, 0, stream>>>(step == 0 ? z : x, x, xsH, xsL);
        for (int s = 0; s < 4; ++s) {
            gemm_mfma<<<dim3(BT / 128, 8), 256, 0, stream>>>(
                xsH, xsL, nullptr, nullptr, WqkH, WqkL,
                nullptr, nullptr, nullptr, nullptr, nullptr, nullptr, nullptr,
                Qhi, Qlo, Khi, Klo, KtrH, KtrL, -1);
            kuramoto_attn<<<dim3(TT / 128, 2, NB * NH), 256, 0, stream>>>(
                Qhi, Qlo, Khi, Klo, KtrH, KtrL, Fp);
            gemm_mfma<<<dim3(BT / 128, 4), 256, 0, stream>>>(
                nullptr, nullptr, Fp, Fp + (size_t)BT * 256, WoutH, WoutL,
                omega, bout, x, kacc, xsH, xsL, x,
                nullptr, nullptr, nullptr, nullptr, nullptr, nullptr, s);
        }
    }
    l2norm_rows<<<BT / 4, 256, 0, stream>>>(x, (float*)d_out, nullptr, nullptr);
}

// Round 8
// 1738.442 us; speedup vs baseline: 2.0394x; 1.1044x over previous
//
#include <hip/hip_runtime.h>
#include <cmath>

#define NB 4
#define TT 2048
#define DD 256
#define NH 4
#define BT (NB*TT)   // 8192 rows

static constexpr float DT_ = 0.25f;

typedef _Float16 f16x8 __attribute__((ext_vector_type(8)));
typedef _Float16 f16x4 __attribute__((ext_vector_type(4)));
typedef float    f32x4 __attribute__((ext_vector_type(4)));

static constexpr size_t HSZ = (size_t)NB * NH * TT * 64;   // per split Q/K array: 2M halves

// ---------------- split W into fp16 hi/lo (runs once per launch) ----------------
__global__ __launch_bounds__(256)
void split_weights(const float* __restrict__ Wqk, const float* __restrict__ Wout,
                   _Float16* __restrict__ WqkH, _Float16* __restrict__ WqkL,
                   _Float16* __restrict__ WoutH, _Float16* __restrict__ WoutL)
{
    const int idx = blockIdx.x * 256 + threadIdx.x;   // float4 group index
    const float4 v = (idx < 32768) ? ((const float4*)Wqk)[idx]
                                   : ((const float4*)Wout)[idx - 32768];
    f16x4 h, l;
    h[0]=(_Float16)v.x; l[0]=(_Float16)(v.x-(float)h[0]);
    h[1]=(_Float16)v.y; l[1]=(_Float16)(v.y-(float)h[1]);
    h[2]=(_Float16)v.z; l[2]=(_Float16)(v.z-(float)h[2]);
    h[3]=(_Float16)v.w; l[3]=(_Float16)(v.w-(float)h[3]);
    if (idx < 32768) { ((f16x4*)WqkH)[idx] = h; ((f16x4*)WqkL)[idx] = l; }
    else { ((f16x4*)WoutH)[idx-32768] = h; ((f16x4*)WoutL)[idx-32768] = l; }
}

// ---------------- row-wise l2 norm over D=256; optional fp16 split emit ----------------
__global__ __launch_bounds__(256)
void l2norm_rows(const float* __restrict__ src, float* __restrict__ dst,
                 _Float16* __restrict__ dstH, _Float16* __restrict__ dstL) {
    const int wave = threadIdx.x >> 6;
    const int lane = threadIdx.x & 63;
    const size_t row = (size_t)blockIdx.x * 4 + wave;
    float4 v = ((const float4*)(src + row * DD))[lane];
    float ss = v.x*v.x + v.y*v.y + v.z*v.z + v.w*v.w;
    #pragma unroll
    for (int off = 32; off; off >>= 1) ss += __shfl_xor(ss, off, 64);
    const float inv = 1.0f / fmaxf(sqrtf(ss), 1e-12f);
    v.x *= inv; v.y *= inv; v.z *= inv; v.w *= inv;
    ((float4*)(dst + row * DD))[lane] = v;
    if (dstH != nullptr) {
        f16x4 h, l;
        h[0]=(_Float16)v.x; l[0]=(_Float16)(v.x-(float)h[0]);
        h[1]=(_Float16)v.y; l[1]=(_Float16)(v.y-(float)h[1]);
        h[2]=(_Float16)v.z; l[2]=(_Float16)(v.z-(float)h[2]);
        h[3]=(_Float16)v.w; l[3]=(_Float16)(v.w-(float)h[3]);
        ((f16x4*)(dstH + row * DD))[lane] = h;
        ((f16x4*)(dstL + row * DD))[lane] = l;
    }
}

// ---------------- split-fp16 MFMA GEMM: C = A[M,256] * W[N,256]^T ----------------
// (unchanged from R7 — passing) Block 256 thr / 4 waves; tile 128m x 64n.
__global__ __launch_bounds__(256)
void gemm_mfma(const _Float16* __restrict__ AH, const _Float16* __restrict__ AL,
               const float* __restrict__ F0, const float* __restrict__ F1,
               const _Float16* __restrict__ BH, const _Float16* __restrict__ BL,
               const float* __restrict__ omega, const float* __restrict__ bout,
               const float* __restrict__ xin, float* __restrict__ kacc,
               _Float16* __restrict__ xsH, _Float16* __restrict__ xsL,
               float* __restrict__ xout,
               _Float16* __restrict__ Qhi, _Float16* __restrict__ Qlo,
               _Float16* __restrict__ Khi, _Float16* __restrict__ Klo,
               _Float16* __restrict__ KtrH, _Float16* __restrict__ KtrL,
               int stage)
{
    __shared__ _Float16 Ah[128 * 72];
    __shared__ _Float16 Al[128 * 72];
    __shared__ _Float16 Bh[64 * 72];
    __shared__ _Float16 Bl[64 * 72];
    const int m0 = blockIdx.x * 128, n0 = blockIdx.y * 64;
    const int t  = threadIdx.x;
    const int w  = t >> 6;
    const int l  = t & 63;
    const int lr = l & 15;
    const int lq = l >> 4;

    f32x4 acc[2][4];
    #pragma unroll
    for (int s = 0; s < 2; ++s)
        #pragma unroll
        for (int nt = 0; nt < 4; ++nt) acc[s][nt] = (f32x4){0.f,0.f,0.f,0.f};

    for (int kc = 0; kc < 4; ++kc) {
        const int k0 = kc * 64;
        __syncthreads();
        if (stage < 0) {
            #pragma unroll
            for (int s2 = 0; s2 < 4; ++s2) {
                const int idx = t + 256 * s2;
                const int r = idx >> 3, c8 = (idx & 7) * 8;
                *(uint4*)&Ah[r * 72 + c8] = *(const uint4*)(AH + (size_t)(m0 + r) * 256 + k0 + c8);
                *(uint4*)&Al[r * 72 + c8] = *(const uint4*)(AL + (size_t)(m0 + r) * 256 + k0 + c8);
            }
        } else {
            #pragma unroll
            for (int s2 = 0; s2 < 4; ++s2) {
                const int idx = t + 256 * s2;
                const int r = idx >> 3, c8 = (idx & 7) * 8;
                const size_t go = (size_t)(m0 + r) * 256 + k0 + c8;
                const float4 a0 = *(const float4*)(F0 + go);
                const float4 a1 = *(const float4*)(F0 + go + 4);
                const float4 b0 = *(const float4*)(F1 + go);
                const float4 b1 = *(const float4*)(F1 + go + 4);
                const float sv[8] = {a0.x+b0.x, a0.y+b0.y, a0.z+b0.z, a0.w+b0.w,
                                     a1.x+b1.x, a1.y+b1.y, a1.z+b1.z, a1.w+b1.w};
                f16x8 hv, lv;
                #pragma unroll
                for (int e = 0; e < 8; ++e) {
                    hv[e] = (_Float16)sv[e];
                    lv[e] = (_Float16)(sv[e] - (float)hv[e]);
                }
                *(f16x8*)&Ah[r * 72 + c8] = hv;
                *(f16x8*)&Al[r * 72 + c8] = lv;
            }
        }
        #pragma unroll
        for (int s2 = 0; s2 < 2; ++s2) {
            const int idx = t + 256 * s2;
            const int r = idx >> 3, c8 = (idx & 7) * 8;
            *(uint4*)&Bh[r * 72 + c8] = *(const uint4*)(BH + (size_t)(n0 + r) * 256 + k0 + c8);
            *(uint4*)&Bl[r * 72 + c8] = *(const uint4*)(BL + (size_t)(n0 + r) * 256 + k0 + c8);
        }
        __syncthreads();
        #pragma unroll
        for (int c = 0; c < 2; ++c) {
            f16x8 ah[2], al[2], bh[4], bl[4];
            #pragma unroll
            for (int s = 0; s < 2; ++s) {
                ah[s] = *(const f16x8*)&Ah[(32*w + 16*s + lr) * 72 + 32*c + 8*lq];
                al[s] = *(const f16x8*)&Al[(32*w + 16*s + lr) * 72 + 32*c + 8*lq];
            }
            #pragma unroll
            for (int nt = 0; nt < 4; ++nt) {
                bh[nt] = *(const f16x8*)&Bh[(16*nt + lr) * 72 + 32*c + 8*lq];
                bl[nt] = *(const f16x8*)&Bl[(16*nt + lr) * 72 + 32*c + 8*lq];
            }
            #pragma unroll
            for (int s = 0; s < 2; ++s)
                #pragma unroll
                for (int nt = 0; nt < 4; ++nt) {
                    acc[s][nt] = __builtin_amdgcn_mfma_f32_16x16x32_f16(ah[s], bh[nt], acc[s][nt], 0, 0, 0);
                    acc[s][nt] = __builtin_amdgcn_mfma_f32_16x16x32_f16(ah[s], bl[nt], acc[s][nt], 0, 0, 0);
                    acc[s][nt] = __builtin_amdgcn_mfma_f32_16x16x32_f16(al[s], bh[nt], acc[s][nt], 0, 0, 0);
                }
        }
    }

    if (stage < 0) {
        float ss[2][4];
        #pragma unroll
        for (int s = 0; s < 2; ++s)
            #pragma unroll
            for (int r = 0; r < 4; ++r) {
                float v = 0.f;
                #pragma unroll
                for (int nt = 0; nt < 4; ++nt) v += acc[s][nt][r] * acc[s][nt][r];
                ss[s][r] = v;
            }
        #pragma unroll
        for (int off = 1; off < 16; off <<= 1)
            #pragma unroll
            for (int s = 0; s < 2; ++s)
                #pragma unroll
                for (int r = 0; r < 4; ++r)
                    ss[s][r] += __shfl_xor(ss[s][r], off, 64);
        const int  b    = m0 >> 11;
        const int  h    = (n0 >> 6) & 3;
        const bool is_k = (n0 >= 256);
        const size_t bhi = (size_t)b * NH + h;
        _Float16* dhi = (is_k ? Khi : Qhi) + bhi * (size_t)TT * 64;
        _Float16* dlo = (is_k ? Klo : Qlo) + bhi * (size_t)TT * 64;
        const int mloc = m0 & (TT - 1);
        #pragma unroll
        for (int s = 0; s < 2; ++s) {
            const int r0 = 32*w + 16*s + 4*lq;
            float inv[4];
            #pragma unroll
            for (int r = 0; r < 4; ++r) inv[r] = 1.0f / fmaxf(sqrtf(ss[s][r]), 1e-12f);
            #pragma unroll
            for (int nt = 0; nt < 4; ++nt) {
                const int d = 16*nt + lr;
                f16x4 hv, lv;
                #pragma unroll
                for (int r = 0; r < 4; ++r) {
                    const float val = acc[s][nt][r] * inv[r];
                    hv[r] = (_Float16)val;
                    lv[r] = (_Float16)(val - (float)hv[r]);
                    dhi[(size_t)(mloc + r0 + r) * 64 + d] = hv[r];
                    dlo[(size_t)(mloc + r0 + r) * 64 + d] = lv[r];
                }
                if (is_k) {
                    const size_t tb = bhi * (size_t)64 * TT + (size_t)d * TT + mloc + r0;
                    *(f16x4*)(KtrH + tb) = hv;
                    *(f16x4*)(KtrL + tb) = lv;
                }
            }
        }
    } else {
        #pragma unroll
        for (int s = 0; s < 2; ++s) {
            const int row0 = m0 + 32*w + 16*s + 4*lq;
            #pragma unroll
            for (int nt = 0; nt < 4; ++nt) {
                const int col = n0 + 16*nt + lr;
                const float ob = omega[col] + bout[col];
                #pragma unroll
                for (int r = 0; r < 4; ++r) {
                    const size_t off = (size_t)(row0 + r) * 256 + col;
                    const float f = acc[s][nt][r] + ob;
                    if (stage == 0) {
                        kacc[off] = f;
                        const float xv = xin[off] + 0.125f * f;
                        const _Float16 xh = (_Float16)xv;
                        xsH[off] = xh;
                        xsL[off] = (_Float16)(xv - (float)xh);
                    } else if (stage < 3) {
                        kacc[off] += 2.0f * f;
                        const float c = (stage == 1) ? 0.125f : 0.25f;
                        const float xv = xin[off] + c * f;
                        const _Float16 xh = (_Float16)xv;
                        xsH[off] = xh;
                        xsL[off] = (_Float16)(xv - (float)xh);
                    } else {
                        xout[off] = xin[off] + (DT_ / 6.0f) * (kacc[off] + f);
                    }
                }
            }
        }
    }
}

// ---------------- F_partial = sin(Q K^T) K over a 1024-j half ----------------
// grid (TT/128, 2, NB*NH) = 512 blocks -> 2 blocks/CU. 32 i-rows/wave.
// R8: GEMM1 computes S^T = K·Q^T (A=K-tile frags — same LDS reads as before;
// B = q regs — same loads). C-layout of S^T puts each lane's 4 values at
// consecutive j in one Pw row -> P staging is 8 ds_write_b64 + 4 ds_read_b128
// per wave-tile (was 32 b32 + 8 b128 + 32 perms). GEMM2 reduced to 2 terms
// (ph·kh + ph·kl): the dropped pl·kh contributes ~5e-4 abs on F — invisible at
// the bf16-quantized output (absmax pinned at 2^-10 since R1).
__global__ __launch_bounds__(256, 2)
void kuramoto_attn(const _Float16* __restrict__ Qhi, const _Float16* __restrict__ Qlo,
                   const _Float16* __restrict__ Khi, const _Float16* __restrict__ Klo,
                   const _Float16* __restrict__ KtrH, const _Float16* __restrict__ KtrL,
                   float* __restrict__ Fp)
{
    __shared__ _Float16 KjH[64 * 72];        // [j][d] hi
    __shared__ _Float16 KjL[64 * 72];        // [j][d] lo
    __shared__ _Float16 KdH[64 * 72];        // [d][j] hi
    __shared__ _Float16 KdL[64 * 72];        // [d][j] lo
    __shared__ _Float16 Pw[4][2][16 * 68];   // per-wave sin(S) hi [s][i_loc][j], pitch 68
    const int bh = blockIdx.z;                     // b*NH + h
    const int b  = bh >> 2, h = bh & 3;
    const size_t base  = (size_t)bh * TT * 64;
    const size_t tbase = (size_t)bh * 64 * TT;
    const int jh0 = blockIdx.y * 1024;
    float* Fout = Fp + (size_t)blockIdx.y * BT * 256;
    const int t = threadIdx.x;
    const int w = t >> 6;
    const int l = t & 63;
    const int lr = l & 15;
    const int lq = l >> 4;
    const int i0 = blockIdx.x * 128 + w * 32;

    f16x8 qh[2][2], ql[2][2];
    #pragma unroll
    for (int s = 0; s < 2; ++s) {
        const size_t qoff = base + (size_t)(i0 + 16*s + lr) * 64 + lq * 8;
        qh[s][0] = *(const f16x8*)(Qhi + qoff);
        qh[s][1] = *(const f16x8*)(Qhi + qoff + 32);
        ql[s][0] = *(const f16x8*)(Qlo + qoff);
        ql[s][1] = *(const f16x8*)(Qlo + qoff + 32);
    }

    f32x4 Facc[2][4];
    #pragma unroll
    for (int s = 0; s < 2; ++s)
        #pragma unroll
        for (int nt = 0; nt < 4; ++nt) Facc[s][nt] = (f32x4){0.f, 0.f, 0.f, 0.f};

    const int sr = t >> 3;
    const int so = (t & 7) * 8;

    for (int j0 = jh0; j0 < jh0 + 1024; j0 += 64) {
        __syncthreads();   // previous tile's LDS reads complete
        {   // direct global -> LDS staging
            *(uint4*)&KjH[sr * 72 + so]        = *(const uint4*)(Khi + base + (size_t)(j0 + sr) * 64 + so);
            *(uint4*)&KjH[(sr + 32) * 72 + so] = *(const uint4*)(Khi + base + (size_t)(j0 + sr + 32) * 64 + so);
            *(uint4*)&KjL[sr * 72 + so]        = *(const uint4*)(Klo + base + (size_t)(j0 + sr) * 64 + so);
            *(uint4*)&KjL[(sr + 32) * 72 + so] = *(const uint4*)(Klo + base + (size_t)(j0 + sr + 32) * 64 + so);
            *(uint4*)&KdH[sr * 72 + so]        = *(const uint4*)(KtrH + tbase + (size_t)sr * TT + j0 + so);
            *(uint4*)&KdH[(sr + 32) * 72 + so] = *(const uint4*)(KtrH + tbase + (size_t)(sr + 32) * TT + j0 + so);
            *(uint4*)&KdL[sr * 72 + so]        = *(const uint4*)(KtrL + tbase + (size_t)sr * TT + j0 + so);
            *(uint4*)&KdL[(sr + 32) * 72 + so] = *(const uint4*)(KtrL + tbase + (size_t)(sr + 32) * TT + j0 + so);
        }
        __syncthreads();
        // GEMM1 (swapped): S^T[j][i] = K·Q^T, 3-term split; sin -> Pw (b64 stores)
        #pragma unroll
        for (int nt = 0; nt < 4; ++nt) {
            f16x8 kh0 = *(const f16x8*)&KjH[(16*nt + lr) * 72 + lq * 8];
            f16x8 kh1 = *(const f16x8*)&KjH[(16*nt + lr) * 72 + 32 + lq * 8];
            f16x8 kl0 = *(const f16x8*)&KjL[(16*nt + lr) * 72 + lq * 8];
            f16x8 kl1 = *(const f16x8*)&KjL[(16*nt + lr) * 72 + 32 + lq * 8];
            #pragma unroll
            for (int s = 0; s < 2; ++s) {
                f32x4 a = (f32x4){0.f, 0.f, 0.f, 0.f};
                a = __builtin_amdgcn_mfma_f32_16x16x32_f16(kh0, qh[s][0], a, 0, 0, 0);
                a = __builtin_amdgcn_mfma_f32_16x16x32_f16(kh1, qh[s][1], a, 0, 0, 0);
                a = __builtin_amdgcn_mfma_f32_16x16x32_f16(kl0, qh[s][0], a, 0, 0, 0);
                a = __builtin_amdgcn_mfma_f32_16x16x32_f16(kl1, qh[s][1], a, 0, 0, 0);
                a = __builtin_amdgcn_mfma_f32_16x16x32_f16(kh0, ql[s][0], a, 0, 0, 0);
                a = __builtin_amdgcn_mfma_f32_16x16x32_f16(kh1, ql[s][1], a, 0, 0, 0);
                // a[r] = S[i = 16s+lr][j = 16nt+4lq+r] — 4 consecutive j, one row
                f16x4 pv;
                #pragma unroll
                for (int r = 0; r < 4; ++r) pv[r] = (_Float16)__sinf(a[r]);
                *(f16x4*)&Pw[w][s][lr * 68 + 16*nt + 4*lq] = pv;
            }
        }
        // GEMM2: F[i][d] += P·K, 2-term (ph·kh + ph·kl)
        f16x8 ph[2][2];
        #pragma unroll
        for (int s = 0; s < 2; ++s) {
            ph[s][0] = *(const f16x8*)&Pw[w][s][lr * 68 + lq * 8];
            ph[s][1] = *(const f16x8*)&Pw[w][s][lr * 68 + 32 + lq * 8];
        }
        #pragma unroll
        for (int nt = 0; nt < 4; ++nt) {
            f16x8 kh0 = *(const f16x8*)&KdH[(16*nt + lr) * 72 + lq * 8];
            f16x8 kh1 = *(const f16x8*)&KdH[(16*nt + lr) * 72 + 32 + lq * 8];
            f16x8 kl0 = *(const f16x8*)&KdL[(16*nt + lr) * 72 + lq * 8];
            f16x8 kl1 = *(const f16x8*)&KdL[(16*nt + lr) * 72 + 32 + lq * 8];
            #pragma unroll
            for (int s = 0; s < 2; ++s) {
                Facc[s][nt] = __builtin_amdgcn_mfma_f32_16x16x32_f16(ph[s][0], kh0, Facc[s][nt], 0, 0, 0);
                Facc[s][nt] = __builtin_amdgcn_mfma_f32_16x16x32_f16(ph[s][1], kh1, Facc[s][nt], 0, 0, 0);
                Facc[s][nt] = __builtin_amdgcn_mfma_f32_16x16x32_f16(ph[s][0], kl0, Facc[s][nt], 0, 0, 0);
                Facc[s][nt] = __builtin_amdgcn_mfma_f32_16x16x32_f16(ph[s][1], kl1, Facc[s][nt], 0, 0, 0);
            }
        }
    }
    // write partial F fp32: row = i0 + 16s + 4lq + r, col = h*64 + 16nt + lr
    #pragma unroll
    for (int s = 0; s < 2; ++s) {
        float* fo = Fout + ((size_t)b * TT + i0 + 16*s + 4*lq) * 256 + h * 64 + lr;
        #pragma unroll
        for (int nt = 0; nt < 4; ++nt)
            #pragma unroll
            for (int r = 0; r < 4; ++r)
                fo[(size_t)r * 256 + nt * 16] = Facc[s][nt][r];
    }
}

extern "C" void kernel_launch(void* const* d_in, const int* in_sizes, int n_in,
                              void* d_out, int out_size, void* d_ws, size_t ws_size,
                              hipStream_t stream) {
    const float* z     = (const float*)d_in[0];
    const float* omega = (const float*)d_in[1];
    const float* Wqk   = (const float*)d_in[2];
    const float* Wout  = (const float*)d_in[3];
    const float* bout  = (const float*)d_in[4];

    float* x    = (float*)d_ws;                  // [BT,256] fp32 state
    float* kacc = x + (size_t)BT * 256;          // [BT,256] fp32 RK4 accumulator
    float* Fp   = kacc + (size_t)BT * 256;       // [2][BT,256] fp32 partial forces
    _Float16* xsH  = (_Float16*)(Fp + (size_t)2 * BT * 256);
    _Float16* xsL  = xsH  + (size_t)BT * 256;
    _Float16* Qhi  = xsL  + (size_t)BT * 256;
    _Float16* Qlo  = Qhi  + HSZ;
    _Float16* Khi  = Qlo  + HSZ;
    _Float16* Klo  = Khi  + HSZ;
    _Float16* KtrH = Klo  + HSZ;
    _Float16* KtrL = KtrH + HSZ;
    _Float16* WqkH = KtrL + HSZ;
    _Float16* WqkL = WqkH + (size_t)512 * 256;
    _Float16* WoutH= WqkL + (size_t)512 * 256;
    _Float16* WoutL= WoutH + (size_t)256 * 256;

    split_weights<<<192, 256, 0, stream>>>(Wqk, Wout, WqkH, WqkL, WoutH, WoutL);

    for (int step = 0; step < 4; ++step) {
        l2norm_rows<<<BT / 4, 256, 0, stream>>>(step == 0 ? z : x, x, xsH, xsL);
        for (int s = 0; s < 4; ++s) {
            gemm_mfma<<<dim3(BT / 128, 8), 256, 0, stream>>>(
                xsH, xsL, nullptr, nullptr, WqkH, WqkL,
                nullptr, nullptr, nullptr, nullptr, nullptr, nullptr, nullptr,
                Qhi, Qlo, Khi, Klo, KtrH, KtrL, -1);
            kuramoto_attn<<<dim3(TT / 128, 2, NB * NH), 256, 0, stream>>>(
                Qhi, Qlo, Khi, Klo, KtrH, KtrL, Fp);
            gemm_mfma<<<dim3(BT / 128, 4), 256, 0, stream>>>(
                nullptr, nullptr, Fp, Fp + (size_t)BT * 256, WoutH, WoutL,
                omega, bout, x, kacc, xsH, xsL, x,
                nullptr, nullptr, nullptr, nullptr, nullptr, nullptr, s);
        }
    }
    l2norm_rows<<<BT / 4, 256, 0, stream>>>(x, (float*)d_out, nullptr, nullptr);
}

// Round 9
// 1299.597 us; speedup vs baseline: 2.7281x; 1.3377x over previous
//
#include <hip/hip_runtime.h>
#include <cmath>

#define NB 4
#define TT 2048
#define DD 256
#define NH 4
#define BT (NB*TT)   // 8192 rows

static constexpr float DT_ = 0.25f;

typedef _Float16 f16x8 __attribute__((ext_vector_type(8)));
typedef _Float16 f16x4 __attribute__((ext_vector_type(4)));
typedef float    f32x4 __attribute__((ext_vector_type(4)));

static constexpr size_t HSZ = (size_t)NB * NH * TT * 64;   // per split Q/K array: 2M halves
static constexpr size_t FSZ = (size_t)BT * 256;            // one partial-F buffer (floats)

// ---------------- split W into fp16 hi/lo (runs once per launch) ----------------
__global__ __launch_bounds__(256)
void split_weights(const float* __restrict__ Wqk, const float* __restrict__ Wout,
                   _Float16* __restrict__ WqkH, _Float16* __restrict__ WqkL,
                   _Float16* __restrict__ WoutH, _Float16* __restrict__ WoutL)
{
    const int idx = blockIdx.x * 256 + threadIdx.x;   // float4 group index
    const float4 v = (idx < 32768) ? ((const float4*)Wqk)[idx]
                                   : ((const float4*)Wout)[idx - 32768];
    f16x4 h, l;
    h[0]=(_Float16)v.x; l[0]=(_Float16)(v.x-(float)h[0]);
    h[1]=(_Float16)v.y; l[1]=(_Float16)(v.y-(float)h[1]);
    h[2]=(_Float16)v.z; l[2]=(_Float16)(v.z-(float)h[2]);
    h[3]=(_Float16)v.w; l[3]=(_Float16)(v.w-(float)h[3]);
    if (idx < 32768) { ((f16x4*)WqkH)[idx] = h; ((f16x4*)WqkL)[idx] = l; }
    else { ((f16x4*)WoutH)[idx-32768] = h; ((f16x4*)WoutL)[idx-32768] = l; }
}

// ---------------- row-wise l2 norm over D=256; optional fp16 split emit ----------------
__global__ __launch_bounds__(256)
void l2norm_rows(const float* __restrict__ src, float* __restrict__ dst,
                 _Float16* __restrict__ dstH, _Float16* __restrict__ dstL) {
    const int wave = threadIdx.x >> 6;
    const int lane = threadIdx.x & 63;
    const size_t row = (size_t)blockIdx.x * 4 + wave;
    float4 v = ((const float4*)(src + row * DD))[lane];
    float ss = v.x*v.x + v.y*v.y + v.z*v.z + v.w*v.w;
    #pragma unroll
    for (int off = 32; off; off >>= 1) ss += __shfl_xor(ss, off, 64);
    const float inv = 1.0f / fmaxf(sqrtf(ss), 1e-12f);
    v.x *= inv; v.y *= inv; v.z *= inv; v.w *= inv;
    ((float4*)(dst + row * DD))[lane] = v;
    if (dstH != nullptr) {
        f16x4 h, l;
        h[0]=(_Float16)v.x; l[0]=(_Float16)(v.x-(float)h[0]);
        h[1]=(_Float16)v.y; l[1]=(_Float16)(v.y-(float)h[1]);
        h[2]=(_Float16)v.z; l[2]=(_Float16)(v.z-(float)h[2]);
        h[3]=(_Float16)v.w; l[3]=(_Float16)(v.w-(float)h[3]);
        ((f16x4*)(dstH + row * DD))[lane] = h;
        ((f16x4*)(dstL + row * DD))[lane] = l;
    }
}

// ---------------- split-fp16 MFMA GEMM: C = A[M,256] * W[N,256]^T ----------------
// Block 256 thr / 4 waves; tile 128m x 64n; K-loop 4 chunks of 64 via LDS.
// stage -1 : A from AH/AL fp16 splits; epilogue = per-head l2norm + Q/K/KtrH emit.
// stage 0-3: A = Fp[0]+Fp[1]+Fp[2] (fp32 partial forces, summed+split in staging);
//            epilogue = f=acc+omega+bout, RK4 update.
__global__ __launch_bounds__(256)
void gemm_mfma(const _Float16* __restrict__ AH, const _Float16* __restrict__ AL,
               const float* __restrict__ Fp,
               const _Float16* __restrict__ BH, const _Float16* __restrict__ BL,
               const float* __restrict__ omega, const float* __restrict__ bout,
               const float* __restrict__ xin, float* __restrict__ kacc,
               _Float16* __restrict__ xsH, _Float16* __restrict__ xsL,
               float* __restrict__ xout,
               _Float16* __restrict__ Qhi, _Float16* __restrict__ Qlo,
               _Float16* __restrict__ Khi, _Float16* __restrict__ Klo,
               _Float16* __restrict__ KtrH,
               int stage)
{
    __shared__ _Float16 Ah[128 * 72];
    __shared__ _Float16 Al[128 * 72];
    __shared__ _Float16 Bh[64 * 72];
    __shared__ _Float16 Bl[64 * 72];
    const int m0 = blockIdx.x * 128, n0 = blockIdx.y * 64;
    const int t  = threadIdx.x;
    const int w  = t >> 6;
    const int l  = t & 63;
    const int lr = l & 15;
    const int lq = l >> 4;

    f32x4 acc[2][4];
    #pragma unroll
    for (int s = 0; s < 2; ++s)
        #pragma unroll
        for (int nt = 0; nt < 4; ++nt) acc[s][nt] = (f32x4){0.f,0.f,0.f,0.f};

    for (int kc = 0; kc < 4; ++kc) {
        const int k0 = kc * 64;
        __syncthreads();
        if (stage < 0) {
            #pragma unroll
            for (int s2 = 0; s2 < 4; ++s2) {
                const int idx = t + 256 * s2;
                const int r = idx >> 3, c8 = (idx & 7) * 8;
                *(uint4*)&Ah[r * 72 + c8] = *(const uint4*)(AH + (size_t)(m0 + r) * 256 + k0 + c8);
                *(uint4*)&Al[r * 72 + c8] = *(const uint4*)(AL + (size_t)(m0 + r) * 256 + k0 + c8);
            }
        } else {
            #pragma unroll
            for (int s2 = 0; s2 < 4; ++s2) {
                const int idx = t + 256 * s2;
                const int r = idx >> 3, c8 = (idx & 7) * 8;
                const size_t go = (size_t)(m0 + r) * 256 + k0 + c8;
                const float4 a0 = *(const float4*)(Fp + go);
                const float4 a1 = *(const float4*)(Fp + go + 4);
                const float4 b0 = *(const float4*)(Fp + FSZ + go);
                const float4 b1 = *(const float4*)(Fp + FSZ + go + 4);
                const float4 c0 = *(const float4*)(Fp + 2*FSZ + go);
                const float4 c1 = *(const float4*)(Fp + 2*FSZ + go + 4);
                const float sv[8] = {a0.x+b0.x+c0.x, a0.y+b0.y+c0.y,
                                     a0.z+b0.z+c0.z, a0.w+b0.w+c0.w,
                                     a1.x+b1.x+c1.x, a1.y+b1.y+c1.y,
                                     a1.z+b1.z+c1.z, a1.w+b1.w+c1.w};
                f16x8 hv, lv;
                #pragma unroll
                for (int e = 0; e < 8; ++e) {
                    hv[e] = (_Float16)sv[e];
                    lv[e] = (_Float16)(sv[e] - (float)hv[e]);
                }
                *(f16x8*)&Ah[r * 72 + c8] = hv;
                *(f16x8*)&Al[r * 72 + c8] = lv;
            }
        }
        #pragma unroll
        for (int s2 = 0; s2 < 2; ++s2) {
            const int idx = t + 256 * s2;
            const int r = idx >> 3, c8 = (idx & 7) * 8;
            *(uint4*)&Bh[r * 72 + c8] = *(const uint4*)(BH + (size_t)(n0 + r) * 256 + k0 + c8);
            *(uint4*)&Bl[r * 72 + c8] = *(const uint4*)(BL + (size_t)(n0 + r) * 256 + k0 + c8);
        }
        __syncthreads();
        #pragma unroll
        for (int c = 0; c < 2; ++c) {
            f16x8 ah[2], al[2], bh[4], bl[4];
            #pragma unroll
            for (int s = 0; s < 2; ++s) {
                ah[s] = *(const f16x8*)&Ah[(32*w + 16*s + lr) * 72 + 32*c + 8*lq];
                al[s] = *(const f16x8*)&Al[(32*w + 16*s + lr) * 72 + 32*c + 8*lq];
            }
            #pragma unroll
            for (int nt = 0; nt < 4; ++nt) {
                bh[nt] = *(const f16x8*)&Bh[(16*nt + lr) * 72 + 32*c + 8*lq];
                bl[nt] = *(const f16x8*)&Bl[(16*nt + lr) * 72 + 32*c + 8*lq];
            }
            #pragma unroll
            for (int s = 0; s < 2; ++s)
                #pragma unroll
                for (int nt = 0; nt < 4; ++nt) {
                    acc[s][nt] = __builtin_amdgcn_mfma_f32_16x16x32_f16(ah[s], bh[nt], acc[s][nt], 0, 0, 0);
                    acc[s][nt] = __builtin_amdgcn_mfma_f32_16x16x32_f16(ah[s], bl[nt], acc[s][nt], 0, 0, 0);
                    acc[s][nt] = __builtin_amdgcn_mfma_f32_16x16x32_f16(al[s], bh[nt], acc[s][nt], 0, 0, 0);
                }
        }
    }

    if (stage < 0) {
        float ss[2][4];
        #pragma unroll
        for (int s = 0; s < 2; ++s)
            #pragma unroll
            for (int r = 0; r < 4; ++r) {
                float v = 0.f;
                #pragma unroll
                for (int nt = 0; nt < 4; ++nt) v += acc[s][nt][r] * acc[s][nt][r];
                ss[s][r] = v;
            }
        #pragma unroll
        for (int off = 1; off < 16; off <<= 1)
            #pragma unroll
            for (int s = 0; s < 2; ++s)
                #pragma unroll
                for (int r = 0; r < 4; ++r)
                    ss[s][r] += __shfl_xor(ss[s][r], off, 64);
        const int  b    = m0 >> 11;
        const int  h    = (n0 >> 6) & 3;
        const bool is_k = (n0 >= 256);
        const size_t bhi = (size_t)b * NH + h;
        _Float16* dhi = (is_k ? Khi : Qhi) + bhi * (size_t)TT * 64;
        _Float16* dlo = (is_k ? Klo : Qlo) + bhi * (size_t)TT * 64;
        const int mloc = m0 & (TT - 1);
        #pragma unroll
        for (int s = 0; s < 2; ++s) {
            const int r0 = 32*w + 16*s + 4*lq;
            float inv[4];
            #pragma unroll
            for (int r = 0; r < 4; ++r) inv[r] = 1.0f / fmaxf(sqrtf(ss[s][r]), 1e-12f);
            #pragma unroll
            for (int nt = 0; nt < 4; ++nt) {
                const int d = 16*nt + lr;
                f16x4 hv, lv;
                #pragma unroll
                for (int r = 0; r < 4; ++r) {
                    const float val = acc[s][nt][r] * inv[r];
                    hv[r] = (_Float16)val;
                    lv[r] = (_Float16)(val - (float)hv[r]);
                    dhi[(size_t)(mloc + r0 + r) * 64 + d] = hv[r];
                    dlo[(size_t)(mloc + r0 + r) * 64 + d] = lv[r];
                }
                if (is_k) {
                    const size_t tb = bhi * (size_t)64 * TT + (size_t)d * TT + mloc + r0;
                    *(f16x4*)(KtrH + tb) = hv;   // KtrL no longer needed (R9)
                }
            }
        }
    } else {
        #pragma unroll
        for (int s = 0; s < 2; ++s) {
            const int row0 = m0 + 32*w + 16*s + 4*lq;
            #pragma unroll
            for (int nt = 0; nt < 4; ++nt) {
                const int col = n0 + 16*nt + lr;
                const float ob = omega[col] + bout[col];
                #pragma unroll
                for (int r = 0; r < 4; ++r) {
                    const size_t off = (size_t)(row0 + r) * 256 + col;
                    const float f = acc[s][nt][r] + ob;
                    if (stage == 0) {
                        kacc[off] = f;
                        const float xv = xin[off] + 0.125f * f;
                        const _Float16 xh = (_Float16)xv;
                        xsH[off] = xh;
                        xsL[off] = (_Float16)(xv - (float)xh);
                    } else if (stage < 3) {
                        kacc[off] += 2.0f * f;
                        const float c = (stage == 1) ? 0.125f : 0.25f;
                        const float xv = xin[off] + c * f;
                        const _Float16 xh = (_Float16)xv;
                        xsH[off] = xh;
                        xsL[off] = (_Float16)(xv - (float)xh);
                    } else {
                        xout[off] = xin[off] + (DT_ / 6.0f) * (kacc[off] + f);
                    }
                }
            }
        }
    }
}

// ---------------- F_partial = sin(Q K^T) K over a j third ----------------
// grid (TT/128, 3, NB*NH) = 768 blocks -> 3 blocks/CU (12 waves/CU).
// j-splits of 11/11/10 64-tiles. LDS = KjH+KjL+KdH+Pw = 45056 B (3x fits 135 KB).
// GEMM1: S^T = K·Q^T 3-term (R8-verified). GEMM2: ph·kh only — dropped ph·kl
// (~5.5e-4 on F, below R8's invisible 9e-4 pl·kh drop); KdL/KtrL eliminated.
__global__ __launch_bounds__(256, 3)
void kuramoto_attn(const _Float16* __restrict__ Qhi, const _Float16* __restrict__ Qlo,
                   const _Float16* __restrict__ Khi, const _Float16* __restrict__ Klo,
                   const _Float16* __restrict__ KtrH,
                   float* __restrict__ Fp)
{
    __shared__ _Float16 KjH[64 * 72];        // [j][d] hi
    __shared__ _Float16 KjL[64 * 72];        // [j][d] lo
    __shared__ _Float16 KdH[64 * 72];        // [d][j] hi
    __shared__ _Float16 Pw[4][2][16 * 68];   // per-wave sin(S) hi [s][i_loc][j]
    const int bh = blockIdx.z;                     // b*NH + h
    const int b  = bh >> 2, h = bh & 3;
    const size_t base  = (size_t)bh * TT * 64;
    const size_t tbase = (size_t)bh * 64 * TT;
    const int t0 = blockIdx.y * 11;                      // first 64-tile of this split
    const int tn = (blockIdx.y == 2) ? 10 : 11;          // tiles in this split
    float* Fout = Fp + (size_t)blockIdx.y * FSZ;
    const int t = threadIdx.x;
    const int w = t >> 6;
    const int l = t & 63;
    const int lr = l & 15;
    const int lq = l >> 4;
    const int i0 = blockIdx.x * 128 + w * 32;

    f16x8 qh[2][2], ql[2][2];
    #pragma unroll
    for (int s = 0; s < 2; ++s) {
        const size_t qoff = base + (size_t)(i0 + 16*s + lr) * 64 + lq * 8;
        qh[s][0] = *(const f16x8*)(Qhi + qoff);
        qh[s][1] = *(const f16x8*)(Qhi + qoff + 32);
        ql[s][0] = *(const f16x8*)(Qlo + qoff);
        ql[s][1] = *(const f16x8*)(Qlo + qoff + 32);
    }

    f32x4 Facc[2][4];
    #pragma unroll
    for (int s = 0; s < 2; ++s)
        #pragma unroll
        for (int nt = 0; nt < 4; ++nt) Facc[s][nt] = (f32x4){0.f, 0.f, 0.f, 0.f};

    const int sr = t >> 3;
    const int so = (t & 7) * 8;

    for (int tt = 0; tt < tn; ++tt) {
        const int j0 = (t0 + tt) * 64;
        __syncthreads();   // previous tile's LDS reads complete
        {   // direct global -> LDS staging (KjH, KjL, KdH)
            *(uint4*)&KjH[sr * 72 + so]        = *(const uint4*)(Khi + base + (size_t)(j0 + sr) * 64 + so);
            *(uint4*)&KjH[(sr + 32) * 72 + so] = *(const uint4*)(Khi + base + (size_t)(j0 + sr + 32) * 64 + so);
            *(uint4*)&KjL[sr * 72 + so]        = *(const uint4*)(Klo + base + (size_t)(j0 + sr) * 64 + so);
            *(uint4*)&KjL[(sr + 32) * 72 + so] = *(const uint4*)(Klo + base + (size_t)(j0 + sr + 32) * 64 + so);
            *(uint4*)&KdH[sr * 72 + so]        = *(const uint4*)(KtrH + tbase + (size_t)sr * TT + j0 + so);
            *(uint4*)&KdH[(sr + 32) * 72 + so] = *(const uint4*)(KtrH + tbase + (size_t)(sr + 32) * TT + j0 + so);
        }
        __syncthreads();
        // GEMM1 (swapped): S^T[j][i] = K·Q^T, 3-term split; sin -> Pw (b64 stores)
        #pragma unroll
        for (int nt = 0; nt < 4; ++nt) {
            f16x8 kh0 = *(const f16x8*)&KjH[(16*nt + lr) * 72 + lq * 8];
            f16x8 kh1 = *(const f16x8*)&KjH[(16*nt + lr) * 72 + 32 + lq * 8];
            f16x8 kl0 = *(const f16x8*)&KjL[(16*nt + lr) * 72 + lq * 8];
            f16x8 kl1 = *(const f16x8*)&KjL[(16*nt + lr) * 72 + 32 + lq * 8];
            #pragma unroll
            for (int s = 0; s < 2; ++s) {
                f32x4 a = (f32x4){0.f, 0.f, 0.f, 0.f};
                a = __builtin_amdgcn_mfma_f32_16x16x32_f16(kh0, qh[s][0], a, 0, 0, 0);
                a = __builtin_amdgcn_mfma_f32_16x16x32_f16(kh1, qh[s][1], a, 0, 0, 0);
                a = __builtin_amdgcn_mfma_f32_16x16x32_f16(kl0, qh[s][0], a, 0, 0, 0);
                a = __builtin_amdgcn_mfma_f32_16x16x32_f16(kl1, qh[s][1], a, 0, 0, 0);
                a = __builtin_amdgcn_mfma_f32_16x16x32_f16(kh0, ql[s][0], a, 0, 0, 0);
                a = __builtin_amdgcn_mfma_f32_16x16x32_f16(kh1, ql[s][1], a, 0, 0, 0);
                // a[r] = S[i = 16s+lr][j = 16nt+4lq+r] — 4 consecutive j, one row
                f16x4 pv;
                #pragma unroll
                for (int r = 0; r < 4; ++r) pv[r] = (_Float16)__sinf(a[r]);
                *(f16x4*)&Pw[w][s][lr * 68 + 16*nt + 4*lq] = pv;
            }
        }
        // GEMM2: F[i][d] += P·K (hi term only)
        f16x8 ph[2][2];
        #pragma unroll
        for (int s = 0; s < 2; ++s) {
            ph[s][0] = *(const f16x8*)&Pw[w][s][lr * 68 + lq * 8];
            ph[s][1] = *(const f16x8*)&Pw[w][s][lr * 68 + 32 + lq * 8];
        }
        #pragma unroll
        for (int nt = 0; nt < 4; ++nt) {
            f16x8 kh0 = *(const f16x8*)&KdH[(16*nt + lr) * 72 + lq * 8];
            f16x8 kh1 = *(const f16x8*)&KdH[(16*nt + lr) * 72 + 32 + lq * 8];
            #pragma unroll
            for (int s = 0; s < 2; ++s) {
                Facc[s][nt] = __builtin_amdgcn_mfma_f32_16x16x32_f16(ph[s][0], kh0, Facc[s][nt], 0, 0, 0);
                Facc[s][nt] = __builtin_amdgcn_mfma_f32_16x16x32_f16(ph[s][1], kh1, Facc[s][nt], 0, 0, 0);
            }
        }
    }
    // write partial F fp32: row = i0 + 16s + 4lq + r, col = h*64 + 16nt + lr
    #pragma unroll
    for (int s = 0; s < 2; ++s) {
        float* fo = Fout + ((size_t)b * TT + i0 + 16*s + 4*lq) * 256 + h * 64 + lr;
        #pragma unroll
        for (int nt = 0; nt < 4; ++nt)
            #pragma unroll
            for (int r = 0; r < 4; ++r)
                fo[(size_t)r * 256 + nt * 16] = Facc[s][nt][r];
    }
}

extern "C" void kernel_launch(void* const* d_in, const int* in_sizes, int n_in,
                              void* d_out, int out_size, void* d_ws, size_t ws_size,
                              hipStream_t stream) {
    const float* z     = (const float*)d_in[0];
    const float* omega = (const float*)d_in[1];
    const float* Wqk   = (const float*)d_in[2];
    const float* Wout  = (const float*)d_in[3];
    const float* bout  = (const float*)d_in[4];

    float* x    = (float*)d_ws;                  // [BT,256] fp32 state
    float* kacc = x + FSZ;                       // [BT,256] fp32 RK4 accumulator
    float* Fp   = kacc + FSZ;                    // [3][BT,256] fp32 partial forces
    _Float16* xsH  = (_Float16*)(Fp + 3 * FSZ);
    _Float16* xsL  = xsH  + FSZ;
    _Float16* Qhi  = xsL  + FSZ;
    _Float16* Qlo  = Qhi  + HSZ;
    _Float16* Khi  = Qlo  + HSZ;
    _Float16* Klo  = Khi  + HSZ;
    _Float16* KtrH = Klo  + HSZ;
    _Float16* WqkH = KtrH + HSZ;
    _Float16* WqkL = WqkH + (size_t)512 * 256;
    _Float16* WoutH= WqkL + (size_t)512 * 256;
    _Float16* WoutL= WoutH + (size_t)256 * 256;

    split_weights<<<192, 256, 0, stream>>>(Wqk, Wout, WqkH, WqkL, WoutH, WoutL);

    for (int step = 0; step < 4; ++step) {
        l2norm_rows<<<BT / 4, 256, 0, stream>>>(step == 0 ? z : x, x, xsH, xsL);
        for (int s = 0; s < 4; ++s) {
            gemm_mfma<<<dim3(BT / 128, 8), 256, 0, stream>>>(
                xsH, xsL, nullptr, WqkH, WqkL,
                nullptr, nullptr, nullptr, nullptr, nullptr, nullptr, nullptr,
                Qhi, Qlo, Khi, Klo, KtrH, -1);
            kuramoto_attn<<<dim3(TT / 128, 3, NB * NH), 256, 0, stream>>>(
                Qhi, Qlo, Khi, Klo, KtrH, Fp);
            gemm_mfma<<<dim3(BT / 128, 4), 256, 0, stream>>>(
                nullptr, nullptr, Fp, WoutH, WoutL,
                omega, bout, x, kacc, xsH, xsL, x,
                nullptr, nullptr, nullptr, nullptr, nullptr, s);
        }
    }
    l2norm_rows<<<BT / 4, 256, 0, stream>>>(x, (float*)d_out, nullptr, nullptr);
}